// Round 1
// baseline (697.308 us; speedup 1.0000x reference)
//
#include <hip/hip_runtime.h>

typedef __attribute__((ext_vector_type(8))) short bf16x8;
typedef __attribute__((ext_vector_type(4))) float f32x4;
typedef __attribute__((address_space(1))) void gvoid_t;
typedef __attribute__((address_space(3))) void lvoid_t;

#define DEVI __device__ __forceinline__

DEVI unsigned short f2bf(float f) {
    unsigned int u = __builtin_bit_cast(unsigned int, f);
    u += 0x7fffu + ((u >> 16) & 1u);   // RNE
    return (unsigned short)(u >> 16);
}

// ---------------- fp32 -> bf16 elementwise (8 elems/thread) ----------------
__global__ void k_convert(const float* __restrict__ in, unsigned short* __restrict__ out, int n8) {
    int i = blockIdx.x * 256 + threadIdx.x;
    if (i >= n8) return;
    const float4* p = (const float4*)in + (size_t)i * 2;
    float4 a = p[0], b = p[1];
    uint4 o;
    o.x = f2bf(a.x) | ((unsigned)f2bf(a.y) << 16);
    o.y = f2bf(a.z) | ((unsigned)f2bf(a.w) << 16);
    o.z = f2bf(b.x) | ((unsigned)f2bf(b.y) << 16);
    o.w = f2bf(b.z) | ((unsigned)f2bf(b.w) << 16);
    *((uint4*)out + i) = o;
}

// ---------------- transpose+convert: w[K][N] f32 -> wt[N][K] bf16 ----------------
__global__ void k_transpose(const float* __restrict__ w, unsigned short* __restrict__ wt, int K, int N) {
    __shared__ float tile[32][33];
    int n0 = blockIdx.x * 32, k0 = blockIdx.y * 32;
    int tx = threadIdx.x, ty = threadIdx.y;
#pragma unroll
    for (int r = 0; r < 32; r += 8)
        tile[ty + r][tx] = w[(size_t)(k0 + ty + r) * N + n0 + tx];
    __syncthreads();
#pragma unroll
    for (int r = 0; r < 32; r += 8)
        wt[(size_t)(n0 + ty + r) * K + k0 + tx] = f2bf(tile[tx][ty + r]);
}

// ---------------- bf16 GEMM: C[M,N] = A[M,K] * Bt[N,K]^T + bias ----------------
// m97 structure: 128x128 tile, BK=32, global_load_lds w16, 4 waves of 64x64.
template <bool OUT_BF16>
__global__ __launch_bounds__(256, 2) void k_gemm(const unsigned short* __restrict__ A,
                                                 const unsigned short* __restrict__ Bt,
                                                 const float* __restrict__ bias,
                                                 void* __restrict__ out,
                                                 int M, int N, int K) {
    __shared__ unsigned short As[128 * 32];
    __shared__ unsigned short Bs[128 * 32];

    int tid = threadIdx.x;
    int nwg = gridDim.x, bid = blockIdx.x;
    // bijective XCD swizzle (m204)
    int q = nwg >> 3, r = nwg & 7;
    int xcd = bid & 7, lid = bid >> 3;
    int swz = ((xcd < r) ? xcd * (q + 1) : r * (q + 1) + (xcd - r) * q) + lid;
    int ntn = N >> 7;
    int bm = swz / ntn, bn = swz % ntn;

    int lane = tid & 63, wid = tid >> 6;
    int wm = (wid & 1) << 6, wn = (wid >> 1) << 6;
    int lr = lane & 15, lg = lane >> 4;

    // staging map: elem e = (p*256+tid)*8 -> row = p*64 + tid/4, col = (tid&3)*8
    int srow = tid >> 2;
    int scol = (tid & 3) << 3;
    const unsigned short* ag = A + (size_t)(bm * 128 + srow) * K + scol;
    const unsigned short* bg = Bt + (size_t)(bn * 128 + srow) * K + scol;

    f32x4 acc[4][4];
#pragma unroll
    for (int i = 0; i < 4; ++i)
#pragma unroll
        for (int j = 0; j < 4; ++j) acc[i][j] = (f32x4){0.f, 0.f, 0.f, 0.f};

    for (int k0 = 0; k0 < K; k0 += 32) {
#pragma unroll
        for (int p = 0; p < 2; ++p) {
            __builtin_amdgcn_global_load_lds((gvoid_t*)(ag + (size_t)p * 64 * K + k0),
                                             (lvoid_t*)(As + p * 2048 + tid * 8), 16, 0, 0);
            __builtin_amdgcn_global_load_lds((gvoid_t*)(bg + (size_t)p * 64 * K + k0),
                                             (lvoid_t*)(Bs + p * 2048 + tid * 8), 16, 0, 0);
        }
        __syncthreads();
        bf16x8 af[4], bfr[4];
#pragma unroll
        for (int mf = 0; mf < 4; ++mf)
            af[mf] = *(const bf16x8*)&As[(wm + mf * 16 + lr) * 32 + lg * 8];
#pragma unroll
        for (int nf = 0; nf < 4; ++nf)
            bfr[nf] = *(const bf16x8*)&Bs[(wn + nf * 16 + lr) * 32 + lg * 8];
#pragma unroll
        for (int mf = 0; mf < 4; ++mf)
#pragma unroll
            for (int nf = 0; nf < 4; ++nf)
                acc[mf][nf] = __builtin_amdgcn_mfma_f32_16x16x32_bf16(af[mf], bfr[nf], acc[mf][nf], 0, 0, 0);
        __syncthreads();
    }

#pragma unroll
    for (int mf = 0; mf < 4; ++mf)
#pragma unroll
        for (int nf = 0; nf < 4; ++nf) {
            int col = bn * 128 + wn + nf * 16 + lr;
            float bv = bias[col];
#pragma unroll
            for (int i = 0; i < 4; ++i) {
                int row = bm * 128 + wm + mf * 16 + lg * 4 + i;
                float v = acc[mf][nf][i] + bv;
                if (OUT_BF16)
                    ((unsigned short*)out)[(size_t)row * N + col] = f2bf(v);
                else
                    ((float*)out)[(size_t)row * N + col] = v;
            }
        }
}

// ---------------- fused flash attention ----------------
// grid = BT*H = 1536 blocks; 4 waves; wave handles 80 query rows (5 m-frags).
// KVBLK=32 (10 tiles). Latent mask: tiles>=2 masked for rows<64.
__global__ __launch_bounds__(256, 1) void k_attn(const unsigned short* __restrict__ qkv,
                                                 unsigned short* __restrict__ y) {
    int bt = blockIdx.x / 12, h = blockIdx.x % 12;
    const unsigned short* Qg = qkv + (size_t)bt * 320 * 2304 + h * 64;
    const unsigned short* Kg = Qg + 768;
    const unsigned short* Vg = Qg + 1536;

    __shared__ unsigned short Vt[64][40];        // V^T (d x s), s-block-swizzled, padded
    __shared__ unsigned short Pl[4][80][40];     // per-wave P, padded rows (80B stride)

    int tid = threadIdx.x, wid = tid >> 6, lane = tid & 63;
    int lr = lane & 15, lg = lane >> 4;
    int q0 = wid * 80;

    // Q fragments in registers (reused across all 10 KV tiles)
    bf16x8 qf[5][2];
#pragma unroll
    for (int mf = 0; mf < 5; ++mf)
#pragma unroll
        for (int kk = 0; kk < 2; ++kk)
            qf[mf][kk] = *(const bf16x8*)(Qg + (size_t)(q0 + mf * 16 + lr) * 2304 + kk * 32 + lg * 8);

    f32x4 o[5][4];
    float mrow[5][4], lsum[5][4];
#pragma unroll
    for (int mf = 0; mf < 5; ++mf) {
#pragma unroll
        for (int i = 0; i < 4; ++i) { mrow[mf][i] = -3e38f; lsum[mf][i] = 0.f; }
#pragma unroll
        for (int nf = 0; nf < 4; ++nf) o[mf][nf] = (f32x4){0.f, 0.f, 0.f, 0.f};
    }

    int vs = tid & 31, vd0 = (tid >> 5) * 8;

    for (int t = 0; t < 10; ++t) {
        int s0 = t * 32;
        {   // stage V^T tile into LDS (swizzled s-blocks to spread banks)
            union { uint4 u; unsigned short s[8]; } vv;
            vv.u = *(const uint4*)(Vg + (size_t)(s0 + vs) * 2304 + vd0);
#pragma unroll
            for (int j = 0; j < 8; ++j) {
                int d = vd0 + j;
                Vt[d][vs ^ (((d >> 3) & 3) << 3)] = vv.s[j];
            }
        }
        __syncthreads();

        // K fragments direct from global (tile is L1/L2 resident)
        bf16x8 kf[2][2];
#pragma unroll
        for (int nf = 0; nf < 2; ++nf)
#pragma unroll
            for (int kk = 0; kk < 2; ++kk)
                kf[nf][kk] = *(const bf16x8*)(Kg + (size_t)(s0 + nf * 16 + lr) * 2304 + kk * 32 + lg * 8);

        // scores
        f32x4 sf[5][2];
#pragma unroll
        for (int mf = 0; mf < 5; ++mf)
#pragma unroll
            for (int nf = 0; nf < 2; ++nf) {
                sf[mf][nf] = (f32x4){0.f, 0.f, 0.f, 0.f};
#pragma unroll
                for (int kk = 0; kk < 2; ++kk)
                    sf[mf][nf] = __builtin_amdgcn_mfma_f32_16x16x32_bf16(qf[mf][kk], kf[nf][kk], sf[mf][nf], 0, 0, 0);
            }

        // online softmax (rows = lg*4+i within each 16-row frag; cols = lr)
#pragma unroll
        for (int mf = 0; mf < 5; ++mf) {
            bool mask = ((q0 + mf * 16) < 64) && (t >= 2);
#pragma unroll
            for (int i = 0; i < 4; ++i) {
                float s0v = sf[mf][0][i] * 0.125f;
                float s1v = sf[mf][1][i] * 0.125f;
                if (mask) { s0v = -3e38f; s1v = -3e38f; }
                float tm = fmaxf(s0v, s1v);
                tm = fmaxf(tm, __shfl_xor(tm, 1));
                tm = fmaxf(tm, __shfl_xor(tm, 2));
                tm = fmaxf(tm, __shfl_xor(tm, 4));
                tm = fmaxf(tm, __shfl_xor(tm, 8));
                float mo = mrow[mf][i];
                float mn = fmaxf(mo, tm);
                float al = __expf(mo - mn);
                mrow[mf][i] = mn;
                float p0 = __expf(s0v - mn);
                float p1 = __expf(s1v - mn);
                float rs = p0 + p1;
                rs += __shfl_xor(rs, 1);
                rs += __shfl_xor(rs, 2);
                rs += __shfl_xor(rs, 4);
                rs += __shfl_xor(rs, 8);
                lsum[mf][i] = lsum[mf][i] * al + rs;
#pragma unroll
                for (int nf = 0; nf < 4; ++nf) o[mf][nf][i] *= al;
                int prow = mf * 16 + lg * 4 + i;
                Pl[wid][prow][lr] = f2bf(p0);
                Pl[wid][prow][16 + lr] = f2bf(p1);
            }
        }
        // per-wave P LDS roundtrip: ensure writes land before the reads below
        asm volatile("s_waitcnt lgkmcnt(0)" ::: "memory");

        bf16x8 pf[5], vf[4];
#pragma unroll
        for (int mf = 0; mf < 5; ++mf)
            pf[mf] = *(const bf16x8*)&Pl[wid][mf * 16 + lr][lg * 8];
#pragma unroll
        for (int nf = 0; nf < 4; ++nf) {
            int d = nf * 16 + lr;
            vf[nf] = *(const bf16x8*)&Vt[d][(lg * 8) ^ (((d >> 3) & 3) << 3)];
        }
#pragma unroll
        for (int mf = 0; mf < 5; ++mf)
#pragma unroll
            for (int nf = 0; nf < 4; ++nf)
                o[mf][nf] = __builtin_amdgcn_mfma_f32_16x16x32_bf16(pf[mf], vf[nf], o[mf][nf], 0, 0, 0);
        __syncthreads();   // protect Vt before next tile's staging
    }

    // epilogue: y = O / l  (bf16)
#pragma unroll
    for (int mf = 0; mf < 5; ++mf)
#pragma unroll
        for (int i = 0; i < 4; ++i) {
            float inv = 1.0f / lsum[mf][i];
            int row = q0 + mf * 16 + lg * 4 + i;
#pragma unroll
            for (int nf = 0; nf < 4; ++nf)
                y[(size_t)(bt * 320 + row) * 768 + h * 64 + nf * 16 + lr] =
                    f2bf(o[mf][nf][i] * inv);
        }
}

// ---------------- launcher ----------------
extern "C" void kernel_launch(void* const* d_in, const int* in_sizes, int n_in,
                              void* d_out, int out_size, void* d_ws, size_t ws_size,
                              hipStream_t stream) {
    const float* x     = (const float*)d_in[0];
    const float* qkv_w = (const float*)d_in[1];
    const float* qkv_b = (const float*)d_in[2];
    const float* out_w = (const float*)d_in[3];
    const float* out_b = (const float*)d_in[4];

    const int M = 40960;  // B*T*S = 4*32*320
    unsigned short* xb  = (unsigned short*)d_ws;
    unsigned short* w1t = xb + (size_t)M * 768;           // [2304][768]
    unsigned short* w2t = w1t + (size_t)2304 * 768;       // [768][768]
    unsigned short* qkv = w2t + (size_t)768 * 768;        // [M][2304]
    unsigned short* yb  = qkv + (size_t)M * 2304;         // [M][768]

    k_convert<<<(M * 768 / 8 + 255) / 256, 256, 0, stream>>>(x, xb, M * 768 / 8);
    k_transpose<<<dim3(2304 / 32, 768 / 32), dim3(32, 8), 0, stream>>>(qkv_w, w1t, 768, 2304);
    k_transpose<<<dim3(768 / 32, 768 / 32), dim3(32, 8), 0, stream>>>(out_w, w2t, 768, 768);

    k_gemm<true><<<(M / 128) * (2304 / 128), 256, 0, stream>>>(xb, w1t, qkv_b, (void*)qkv, M, 2304, 768);
    k_attn<<<128 * 12, 256, 0, stream>>>(qkv, yb);
    k_gemm<false><<<(M / 128) * (768 / 128), 256, 0, stream>>>(yb, w2t, out_b, d_out, M, 768, 768);
}

// Round 4
// 467.969 us; speedup vs baseline: 1.4901x; 1.4901x over previous
//
#include <hip/hip_runtime.h>

typedef __attribute__((ext_vector_type(8))) short bf16x8;
typedef __attribute__((ext_vector_type(4))) float f32x4;
typedef __attribute__((ext_vector_type(16))) float f32x16;
typedef __attribute__((address_space(1))) void gvoid_t;
typedef __attribute__((address_space(3))) void lvoid_t;

#define DEVI __device__ __forceinline__

DEVI unsigned short f2bf(float f) {
    unsigned int u = __builtin_bit_cast(unsigned int, f);
    u += 0x7fffu + ((u >> 16) & 1u);   // RNE
    return (unsigned short)(u >> 16);
}

DEVI unsigned cvt_pk_bf16(float a, float b) {
    unsigned r;
    asm("v_cvt_pk_bf16_f32 %0, %1, %2" : "=v"(r) : "v"(a), "v"(b));
    return r;
}

// ---------------- fp32 -> bf16 elementwise (8 elems/thread) ----------------
__global__ void k_convert(const float* __restrict__ in, unsigned short* __restrict__ out, int n8) {
    int i = blockIdx.x * 256 + threadIdx.x;
    if (i >= n8) return;
    const float4* p = (const float4*)in + (size_t)i * 2;
    float4 a = p[0], b = p[1];
    uint4 o;
    o.x = f2bf(a.x) | ((unsigned)f2bf(a.y) << 16);
    o.y = f2bf(a.z) | ((unsigned)f2bf(a.w) << 16);
    o.z = f2bf(b.x) | ((unsigned)f2bf(b.y) << 16);
    o.w = f2bf(b.z) | ((unsigned)f2bf(b.w) << 16);
    *((uint4*)out + i) = o;
}

// ---------------- transpose+convert: w[K][N] f32 -> wt[N][K] bf16 ----------------
__global__ void k_transpose(const float* __restrict__ w, unsigned short* __restrict__ wt, int K, int N) {
    __shared__ float tile[32][33];
    int n0 = blockIdx.x * 32, k0 = blockIdx.y * 32;
    int tx = threadIdx.x, ty = threadIdx.y;
#pragma unroll
    for (int r = 0; r < 32; r += 8)
        tile[ty + r][tx] = w[(size_t)(k0 + ty + r) * N + n0 + tx];
    __syncthreads();
#pragma unroll
    for (int r = 0; r < 32; r += 8)
        wt[(size_t)(n0 + ty + r) * K + k0 + tx] = f2bf(tile[tx][ty + r]);
}

// ---------------- bf16 GEMM: C[M,N] = A[M,K] * Bt[N,K]^T + bias ----------------
template <bool OUT_BF16>
__global__ __launch_bounds__(256, 2) void k_gemm(const unsigned short* __restrict__ A,
                                                 const unsigned short* __restrict__ Bt,
                                                 const float* __restrict__ bias,
                                                 void* __restrict__ out,
                                                 int M, int N, int K) {
    __shared__ unsigned short As[128 * 32];
    __shared__ unsigned short Bs[128 * 32];

    int tid = threadIdx.x;
    int nwg = gridDim.x, bid = blockIdx.x;
    int q = nwg >> 3, r = nwg & 7;
    int xcd = bid & 7, lid = bid >> 3;
    int swz = ((xcd < r) ? xcd * (q + 1) : r * (q + 1) + (xcd - r) * q) + lid;
    int ntn = N >> 7;
    int bm = swz / ntn, bn = swz % ntn;

    int lane = tid & 63, wid = tid >> 6;
    int wm = (wid & 1) << 6, wn = (wid >> 1) << 6;
    int lr = lane & 15, lg = lane >> 4;

    int srow = tid >> 2;
    int scol = (tid & 3) << 3;
    const unsigned short* ag = A + (size_t)(bm * 128 + srow) * K + scol;
    const unsigned short* bg = Bt + (size_t)(bn * 128 + srow) * K + scol;

    f32x4 acc[4][4];
#pragma unroll
    for (int i = 0; i < 4; ++i)
#pragma unroll
        for (int j = 0; j < 4; ++j) acc[i][j] = (f32x4){0.f, 0.f, 0.f, 0.f};

    for (int k0 = 0; k0 < K; k0 += 32) {
#pragma unroll
        for (int p = 0; p < 2; ++p) {
            __builtin_amdgcn_global_load_lds((gvoid_t*)(ag + (size_t)p * 64 * K + k0),
                                             (lvoid_t*)(As + p * 2048 + tid * 8), 16, 0, 0);
            __builtin_amdgcn_global_load_lds((gvoid_t*)(bg + (size_t)p * 64 * K + k0),
                                             (lvoid_t*)(Bs + p * 2048 + tid * 8), 16, 0, 0);
        }
        __syncthreads();
        bf16x8 af[4], bfr[4];
#pragma unroll
        for (int mf = 0; mf < 4; ++mf)
            af[mf] = *(const bf16x8*)&As[(wm + mf * 16 + lr) * 32 + lg * 8];
#pragma unroll
        for (int nf = 0; nf < 4; ++nf)
            bfr[nf] = *(const bf16x8*)&Bs[(wn + nf * 16 + lr) * 32 + lg * 8];
#pragma unroll
        for (int mf = 0; mf < 4; ++mf)
#pragma unroll
            for (int nf = 0; nf < 4; ++nf)
                acc[mf][nf] = __builtin_amdgcn_mfma_f32_16x16x32_bf16(af[mf], bfr[nf], acc[mf][nf], 0, 0, 0);
        __syncthreads();
    }

#pragma unroll
    for (int mf = 0; mf < 4; ++mf)
#pragma unroll
        for (int nf = 0; nf < 4; ++nf) {
            int col = bn * 128 + wn + nf * 16 + lr;
            float bv = bias[col];
#pragma unroll
            for (int i = 0; i < 4; ++i) {
                int row = bm * 128 + wm + mf * 16 + lg * 4 + i;
                float v = acc[mf][nf][i] + bv;
                if (OUT_BF16)
                    ((unsigned short*)out)[(size_t)row * N + col] = f2bf(v);
                else
                    ((float*)out)[(size_t)row * N + col] = v;
            }
        }
}

// ---------------- fused flash attention v2 (swapped-QK, 32x32, in-register softmax) ----
// Block = (bt,h): 10 waves, wave w owns q-tile w (rows w*32..w*32+31).
// Latent waves (w<2, rows<64) attend only KV tiles 0,1 -> mask is free.
// S^T = mfma(K,Q): lane l holds q=l&31, half hh=l>>5; p-row in 16 regs.
__global__ __launch_bounds__(640) void k_attn2(const unsigned short* __restrict__ qkv,
                                               unsigned short* __restrict__ y) {
    int bt = blockIdx.x / 12, h = blockIdx.x % 12;
    const unsigned short* Qg = qkv + (size_t)bt * 320 * 2304 + h * 64;
    const unsigned short* Kg = Qg + 768;
    const unsigned short* Vg = Qg + 1536;

    __shared__ unsigned short Vt[64 * 40];   // V^T [d][k'], stride 40, k-block swizzled

    int tid = threadIdx.x, w = tid >> 6, l = tid & 63;
    int q = l & 31, hh = l >> 5;
    int q0 = w * 32;
    int ntile = (w < 2) ? 2 : 10;

    // Q B-fragments (B[k=hd][col=q]): lane reads Q[q0+q][c*16+hh*8 .. +8]
    bf16x8 qf[4];
#pragma unroll
    for (int c = 0; c < 4; ++c)
        qf[c] = *(const bf16x8*)(Qg + (size_t)(q0 + q) * 2304 + c * 16 + hh * 8);

    f32x16 o0 = (f32x16)0.f, o1 = (f32x16)0.f;
    float m = -3e38f, lsum = 0.f;
    const float SC = 0.125f * 1.44269504089f;   // 1/sqrt(64) * log2(e)

    for (int t = 0; t < 10; ++t) {
        // cooperative V^T staging (threads 0..511): V[t*32+sk][sd..sd+3] -> Vt[d][sk^swz]
        if (tid < 512) {
            int sk = tid >> 4;
            int sd = (tid & 15) * 4;
            union { uint2 u; unsigned short s[4]; } vv;
            vv.u = *(const uint2*)(Vg + (size_t)(t * 32 + sk) * 2304 + sd);
#pragma unroll
            for (int j = 0; j < 4; ++j) {
                int d = sd + j;
                Vt[d * 40 + (sk ^ (((d >> 3) & 3) << 3))] = vv.s[j];
            }
        }
        __syncthreads();

        if (t < ntile) {
            int s0 = t * 32;
            // K A-fragments direct from global (L1/L2-resident, shared across waves)
            bf16x8 kf[4];
#pragma unroll
            for (int c = 0; c < 4; ++c)
                kf[c] = *(const bf16x8*)(Kg + (size_t)(s0 + q) * 2304 + c * 16 + hh * 8);

            f32x16 sacc = (f32x16)0.f;
#pragma unroll
            for (int c = 0; c < 4; ++c)
                sacc = __builtin_amdgcn_mfma_f32_32x32x16_bf16(kf[c], qf[c], sacc, 0, 0, 0);

            // in-register online softmax (exp2 domain)
            float p[16];
            float tm = -3e38f;
#pragma unroll
            for (int r = 0; r < 16; ++r) {
                p[r] = sacc[r] * SC;
                tm = fmaxf(tm, p[r]);
            }
            tm = fmaxf(tm, __shfl_xor(tm, 32));
            if (!__all(tm <= m + 8.f)) {       // defer-max (T13)
                float mn = fmaxf(m, tm);
                float al = __builtin_amdgcn_exp2f(m - mn);
                lsum *= al;
#pragma unroll
                for (int r = 0; r < 16; ++r) { o0[r] *= al; o1[r] *= al; }
                m = mn;
            }
#pragma unroll
            for (int r = 0; r < 16; ++r) {
                p[r] = __builtin_amdgcn_exp2f(p[r] - m);
                lsum += p[r];
            }

            // P -> bf16 B-fragments via cvt_pk + permlane32_swap (T12)
            unsigned a0 = cvt_pk_bf16(p[0], p[1]);
            unsigned a1 = cvt_pk_bf16(p[2], p[3]);
            unsigned b0 = cvt_pk_bf16(p[4], p[5]);
            unsigned b1 = cvt_pk_bf16(p[6], p[7]);
            asm("v_permlane32_swap_b32 %0, %1" : "+v"(a0), "+v"(b0));
            asm("v_permlane32_swap_b32 %0, %1" : "+v"(a1), "+v"(b1));
            unsigned c0 = cvt_pk_bf16(p[8], p[9]);
            unsigned c1 = cvt_pk_bf16(p[10], p[11]);
            unsigned d0 = cvt_pk_bf16(p[12], p[13]);
            unsigned d1 = cvt_pk_bf16(p[14], p[15]);
            asm("v_permlane32_swap_b32 %0, %1" : "+v"(c0), "+v"(d0));
            asm("v_permlane32_swap_b32 %0, %1" : "+v"(c1), "+v"(d1));
            union { unsigned u[4]; bf16x8 v; } pf0, pf1;
            pf0.u[0] = a0; pf0.u[1] = a1; pf0.u[2] = b0; pf0.u[3] = b1;
            pf1.u[0] = c0; pf1.u[1] = c1; pf1.u[2] = d0; pf1.u[3] = d1;

            // PV: O^T += V^T(frag) * P^T(frag); kc=0 -> pf0, kc=1 -> pf1 for BOTH d-tiles
            {
                int d = q;
                int sw = (d >> 3) & 3;
                bf16x8 va0 = *(const bf16x8*)&Vt[d * 40 + ((0 + hh) ^ sw) * 8];
                bf16x8 va1 = *(const bf16x8*)&Vt[d * 40 + ((2 + hh) ^ sw) * 8];
                o0 = __builtin_amdgcn_mfma_f32_32x32x16_bf16(va0, pf0.v, o0, 0, 0, 0);
                o0 = __builtin_amdgcn_mfma_f32_32x32x16_bf16(va1, pf1.v, o0, 0, 0, 0);
            }
            {
                int d = 32 + q;
                int sw = (d >> 3) & 3;
                bf16x8 va0 = *(const bf16x8*)&Vt[d * 40 + ((0 + hh) ^ sw) * 8];
                bf16x8 va1 = *(const bf16x8*)&Vt[d * 40 + ((2 + hh) ^ sw) * 8];
                o1 = __builtin_amdgcn_mfma_f32_32x32x16_bf16(va0, pf0.v, o1, 0, 0, 0);
                o1 = __builtin_amdgcn_mfma_f32_32x32x16_bf16(va1, pf1.v, o1, 0, 0, 0);
            }
        }
        __syncthreads();
    }

    // epilogue: y = O^T / l   (lane l holds q=l&31; d-rows per 32x32 C mapping)
    lsum += __shfl_xor(lsum, 32);
    float inv = 1.f / lsum;
    unsigned short* yp = y + (size_t)(bt * 320 + q0 + q) * 768 + h * 64;
#pragma unroll
    for (int r = 0; r < 16; r += 2) {
        int dr = (r & 3) + 8 * (r >> 2) + 4 * hh;   // row of even reg; r+1 is dr+1
        *(unsigned*)(yp + dr) =
            (unsigned)f2bf(o0[r] * inv) | ((unsigned)f2bf(o0[r + 1] * inv) << 16);
        *(unsigned*)(yp + 32 + dr) =
            (unsigned)f2bf(o1[r] * inv) | ((unsigned)f2bf(o1[r + 1] * inv) << 16);
    }
}

// ---------------- launcher ----------------
extern "C" void kernel_launch(void* const* d_in, const int* in_sizes, int n_in,
                              void* d_out, int out_size, void* d_ws, size_t ws_size,
                              hipStream_t stream) {
    const float* x     = (const float*)d_in[0];
    const float* qkv_w = (const float*)d_in[1];
    const float* qkv_b = (const float*)d_in[2];
    const float* out_w = (const float*)d_in[3];
    const float* out_b = (const float*)d_in[4];

    const int M = 40960;  // B*T*S = 4*32*320
    unsigned short* xb  = (unsigned short*)d_ws;
    unsigned short* w1t = xb + (size_t)M * 768;           // [2304][768]
    unsigned short* w2t = w1t + (size_t)2304 * 768;       // [768][768]
    unsigned short* qkv = w2t + (size_t)768 * 768;        // [M][2304]
    unsigned short* yb  = qkv + (size_t)M * 2304;         // [M][768]

    k_convert<<<(M * 768 / 8 + 255) / 256, 256, 0, stream>>>(x, xb, M * 768 / 8);
    k_transpose<<<dim3(2304 / 32, 768 / 32), dim3(32, 8), 0, stream>>>(qkv_w, w1t, 768, 2304);
    k_transpose<<<dim3(768 / 32, 768 / 32), dim3(32, 8), 0, stream>>>(out_w, w2t, 768, 768);

    k_gemm<true><<<(M / 128) * (2304 / 128), 256, 0, stream>>>(xb, w1t, qkv_b, (void*)qkv, M, 2304, 768);
    k_attn2<<<128 * 12, 640, 0, stream>>>(qkv, yb);
    k_gemm<false><<<(M / 128) * (768 / 128), 256, 0, stream>>>(yb, w2t, out_b, d_out, M, 768, 768);
}

// Round 5
// 438.668 us; speedup vs baseline: 1.5896x; 1.0668x over previous
//
#include <hip/hip_runtime.h>

typedef __attribute__((ext_vector_type(8))) short bf16x8;
typedef __attribute__((ext_vector_type(4))) float f32x4;
typedef __attribute__((ext_vector_type(16))) float f32x16;
typedef __attribute__((address_space(1))) void gvoid_t;
typedef __attribute__((address_space(3))) void lvoid_t;

#define DEVI __device__ __forceinline__

DEVI unsigned short f2bf(float f) {
    unsigned int u = __builtin_bit_cast(unsigned int, f);
    u += 0x7fffu + ((u >> 16) & 1u);   // RNE
    return (unsigned short)(u >> 16);
}

DEVI unsigned cvt_pk_bf16(float a, float b) {
    unsigned r;
    asm("v_cvt_pk_bf16_f32 %0, %1, %2" : "=v"(r) : "v"(a), "v"(b));
    return r;
}

DEVI f32x4 mfma16(bf16x8 a, bf16x8 b, f32x4 c) {
    return __builtin_amdgcn_mfma_f32_16x16x32_bf16(a, b, c, 0, 0, 0);
}

// ---------------- fp32 -> bf16 elementwise (8 elems/thread) ----------------
__global__ void k_convert(const float* __restrict__ in, unsigned short* __restrict__ out, int n8) {
    int i = blockIdx.x * 256 + threadIdx.x;
    if (i >= n8) return;
    const float4* p = (const float4*)in + (size_t)i * 2;
    float4 a = p[0], b = p[1];
    uint4 o;
    o.x = f2bf(a.x) | ((unsigned)f2bf(a.y) << 16);
    o.y = f2bf(a.z) | ((unsigned)f2bf(a.w) << 16);
    o.z = f2bf(b.x) | ((unsigned)f2bf(b.y) << 16);
    o.w = f2bf(b.z) | ((unsigned)f2bf(b.w) << 16);
    *((uint4*)out + i) = o;
}

// ---------------- transpose+convert: w[K][N] f32 -> wt[N][K] bf16 ----------------
__global__ void k_transpose(const float* __restrict__ w, unsigned short* __restrict__ wt, int K, int N) {
    __shared__ float tile[32][33];
    int n0 = blockIdx.x * 32, k0 = blockIdx.y * 32;
    int tx = threadIdx.x, ty = threadIdx.y;
#pragma unroll
    for (int r = 0; r < 32; r += 8)
        tile[ty + r][tx] = w[(size_t)(k0 + ty + r) * N + n0 + tx];
    __syncthreads();
#pragma unroll
    for (int r = 0; r < 32; r += 8)
        wt[(size_t)(n0 + ty + r) * K + k0 + tx] = f2bf(tile[tx][ty + r]);
}

// ---------------- 256x256 8-phase bf16 GEMM: C[M,N] = A[M,K]*Bt[N,K]^T + bias --------
// 512 threads = 8 waves (2M x 4N); wave C-tile 128x64. BK=64, 2 K-tiles dbuf in LDS.
// Per K-tile 4 phases (snake (0,0),(0,1),(1,1),(1,0)); counted vmcnt(2) at tile end.
// LDS swizzle: col ^= (row&7)<<3 elements, applied inverse on global staging src.
template <bool OUT_BF16>
__global__ __launch_bounds__(512, 2) void k_gemm256(const unsigned short* __restrict__ A,
                                                    const unsigned short* __restrict__ Bt,
                                                    const float* __restrict__ bias,
                                                    void* __restrict__ out,
                                                    int M, int N, int K) {
    __shared__ unsigned short smem[65536];   // A[2][256][64] @0, B[2][256][64] @32768

    const int tid = threadIdx.x;
    const int nwg = gridDim.x, bid = blockIdx.x;
    const int q8 = nwg >> 3, r8 = nwg & 7;
    const int xcd = bid & 7, lid = bid >> 3;
    const int swz = ((xcd < r8) ? xcd * (q8 + 1) : r8 * (q8 + 1) + (xcd - r8) * q8) + lid;
    const int ntn = N >> 8;
    const int bm = swz / ntn, bn = swz % ntn;

    const int lane = tid & 63, wid = tid >> 6;
    const int wr = wid >> 2, wc = wid & 3;
    const int lr = lane & 15, lg = lane >> 4;
    const int cswz = (lr & 7) << 3;                 // read-side col XOR (elements)
    const int col0 = (lg * 8) ^ cswz;               // kk=1 toggles bit 5 (elem 32)

    const int NT = K >> 6;

    // staging source (inverse-swizzled): load-quarter q covers rows q*64+(tid>>3)
    const int srowl = tid >> 3;
    const int scole = ((tid & 7) ^ (srowl & 7)) << 3;
    const unsigned short* aSrc = A  + (size_t)(bm * 256 + srowl) * K + scole;
    const unsigned short* bSrc = Bt + (size_t)(bn * 256 + srowl) * K + scole;

#define STG(matOff, srcBase, qq, koff, bufw)                                              \
    __builtin_amdgcn_global_load_lds((gvoid_t*)((srcBase) + (size_t)(qq) * 64 * K + (koff)), \
        (lvoid_t*)(smem + (matOff) + (bufw) * 16384 + (qq) * 4096 + tid * 8), 16, 0, 0)

    f32x4 acc[8][4];
#pragma unroll
    for (int i = 0; i < 8; ++i)
#pragma unroll
        for (int j = 0; j < 4; ++j) acc[i][j] = (f32x4){0.f, 0.f, 0.f, 0.f};

    // prologue: tile0 fully (8 loads) + tile1 A-L0, A-L2
    {
        const int k1 = (NT > 1) ? 64 : 0;
        STG(0, aSrc, 0, 0, 0); STG(0, aSrc, 1, 0, 0); STG(0, aSrc, 2, 0, 0); STG(0, aSrc, 3, 0, 0);
        STG(32768, bSrc, 0, 0, 0); STG(32768, bSrc, 1, 0, 0); STG(32768, bSrc, 2, 0, 0); STG(32768, bSrc, 3, 0, 0);
        STG(0, aSrc, 0, k1, 1); STG(0, aSrc, 2, k1, 1);
        asm volatile("s_waitcnt vmcnt(2)" ::: "memory");
        __builtin_amdgcn_s_barrier();
    }

#pragma unroll 1
    for (int t = 0; t < NT; ++t) {
        const int bufR = t & 1, bufW = bufR ^ 1;
        const int ko1 = (t + 1 < NT) ? (t + 1) * 64 : 0;
        const int ko2 = (t + 2 < NT) ? (t + 2) * 64 : 0;
        const unsigned short* abuf = smem + bufR * 16384;
        const unsigned short* bbuf = smem + 32768 + bufR * 16384;
        bf16x8 af[4][2], bfr[2][2];

        // ---- phase 0: (mh=0, nh=0) ----
#pragma unroll
        for (int mf = 0; mf < 4; ++mf)
#pragma unroll
            for (int kk = 0; kk < 2; ++kk)
                af[mf][kk] = *(const bf16x8*)(abuf + (wr * 128 + mf * 16 + lr) * 64 + (col0 ^ (kk * 32)));
#pragma unroll
        for (int j = 0; j < 2; ++j)
#pragma unroll
            for (int kk = 0; kk < 2; ++kk)
                bfr[j][kk] = *(const bf16x8*)(bbuf + (wc * 64 + j * 16 + lr) * 64 + (col0 ^ (kk * 32)));
        STG(32768, bSrc, 0, ko1, bufW); STG(32768, bSrc, 1, ko1, bufW);
        __builtin_amdgcn_s_barrier();
        asm volatile("s_waitcnt lgkmcnt(0)" ::: "memory");
        __builtin_amdgcn_sched_barrier(0);
        __builtin_amdgcn_s_setprio(1);
#pragma unroll
        for (int mf = 0; mf < 4; ++mf)
#pragma unroll
            for (int j = 0; j < 2; ++j)
#pragma unroll
                for (int kk = 0; kk < 2; ++kk)
                    acc[mf][j] = mfma16(af[mf][kk], bfr[j][kk], acc[mf][j]);
        __builtin_amdgcn_s_setprio(0);
        __builtin_amdgcn_s_barrier();

        // ---- phase 1: (mh=0, nh=1) ----
#pragma unroll
        for (int j = 0; j < 2; ++j)
#pragma unroll
            for (int kk = 0; kk < 2; ++kk)
                bfr[j][kk] = *(const bf16x8*)(bbuf + (wc * 64 + (2 + j) * 16 + lr) * 64 + (col0 ^ (kk * 32)));
        STG(32768, bSrc, 2, ko1, bufW); STG(32768, bSrc, 3, ko1, bufW);
        __builtin_amdgcn_s_barrier();
        asm volatile("s_waitcnt lgkmcnt(0)" ::: "memory");
        __builtin_amdgcn_sched_barrier(0);
        __builtin_amdgcn_s_setprio(1);
#pragma unroll
        for (int mf = 0; mf < 4; ++mf)
#pragma unroll
            for (int j = 0; j < 2; ++j)
#pragma unroll
                for (int kk = 0; kk < 2; ++kk)
                    acc[mf][2 + j] = mfma16(af[mf][kk], bfr[j][kk], acc[mf][2 + j]);
        __builtin_amdgcn_s_setprio(0);
        __builtin_amdgcn_s_barrier();

        // ---- phase 2: (mh=1, nh=1) ----
#pragma unroll
        for (int mf = 0; mf < 4; ++mf)
#pragma unroll
            for (int kk = 0; kk < 2; ++kk)
                af[mf][kk] = *(const bf16x8*)(abuf + (wr * 128 + 64 + mf * 16 + lr) * 64 + (col0 ^ (kk * 32)));
        STG(0, aSrc, 1, ko1, bufW); STG(0, aSrc, 3, ko1, bufW);
        __builtin_amdgcn_s_barrier();
        asm volatile("s_waitcnt lgkmcnt(0)" ::: "memory");
        __builtin_amdgcn_sched_barrier(0);
        __builtin_amdgcn_s_setprio(1);
#pragma unroll
        for (int mf = 0; mf < 4; ++mf)
#pragma unroll
            for (int j = 0; j < 2; ++j)
#pragma unroll
                for (int kk = 0; kk < 2; ++kk)
                    acc[4 + mf][2 + j] = mfma16(af[mf][kk], bfr[j][kk], acc[4 + mf][2 + j]);
        __builtin_amdgcn_s_setprio(0);
        __builtin_amdgcn_s_barrier();

        // ---- phase 3: (mh=1, nh=0); stages t+2 A-L0/L2 into bufR (regions dead since ph1) ----
#pragma unroll
        for (int j = 0; j < 2; ++j)
#pragma unroll
            for (int kk = 0; kk < 2; ++kk)
                bfr[j][kk] = *(const bf16x8*)(bbuf + (wc * 64 + j * 16 + lr) * 64 + (col0 ^ (kk * 32)));
        STG(0, aSrc, 0, ko2, bufR); STG(0, aSrc, 2, ko2, bufR);
        __builtin_amdgcn_s_barrier();
        asm volatile("s_waitcnt lgkmcnt(0)" ::: "memory");
        __builtin_amdgcn_sched_barrier(0);
        __builtin_amdgcn_s_setprio(1);
#pragma unroll
        for (int mf = 0; mf < 4; ++mf)
#pragma unroll
            for (int j = 0; j < 2; ++j)
#pragma unroll
                for (int kk = 0; kk < 2; ++kk)
                    acc[4 + mf][j] = mfma16(af[mf][kk], bfr[j][kk], acc[4 + mf][j]);
        __builtin_amdgcn_s_setprio(0);
        asm volatile("s_waitcnt vmcnt(2)" ::: "memory");
        __builtin_amdgcn_s_barrier();
    }
#undef STG

    // epilogue
#pragma unroll
    for (int mf = 0; mf < 8; ++mf)
#pragma unroll
        for (int nf = 0; nf < 4; ++nf) {
            int col = bn * 256 + wc * 64 + nf * 16 + lr;
            float bv = bias[col];
#pragma unroll
            for (int i = 0; i < 4; ++i) {
                int row = bm * 256 + wr * 128 + mf * 16 + lg * 4 + i;
                float v = acc[mf][nf][i] + bv;
                if (OUT_BF16)
                    ((unsigned short*)out)[(size_t)row * N + col] = f2bf(v);
                else
                    ((float*)out)[(size_t)row * N + col] = v;
            }
        }
}

// ---------------- fused flash attention v2 (swapped-QK, 32x32, in-register softmax) ----
__global__ __launch_bounds__(640) void k_attn2(const unsigned short* __restrict__ qkv,
                                               unsigned short* __restrict__ y) {
    int bt = blockIdx.x / 12, h = blockIdx.x % 12;
    const unsigned short* Qg = qkv + (size_t)bt * 320 * 2304 + h * 64;
    const unsigned short* Kg = Qg + 768;
    const unsigned short* Vg = Qg + 1536;

    __shared__ unsigned short Vt[64 * 40];   // V^T [d][k'], stride 40, k-block swizzled

    int tid = threadIdx.x, w = tid >> 6, l = tid & 63;
    int q = l & 31, hh = l >> 5;
    int q0 = w * 32;
    int ntile = (w < 2) ? 2 : 10;

    bf16x8 qf[4];
#pragma unroll
    for (int c = 0; c < 4; ++c)
        qf[c] = *(const bf16x8*)(Qg + (size_t)(q0 + q) * 2304 + c * 16 + hh * 8);

    f32x16 o0 = (f32x16)0.f, o1 = (f32x16)0.f;
    float m = -3e38f, lsum = 0.f;
    const float SC = 0.125f * 1.44269504089f;

    for (int t = 0; t < 10; ++t) {
        if (tid < 512) {
            int sk = tid >> 4;
            int sd = (tid & 15) * 4;
            union { uint2 u; unsigned short s[4]; } vv;
            vv.u = *(const uint2*)(Vg + (size_t)(t * 32 + sk) * 2304 + sd);
#pragma unroll
            for (int j = 0; j < 4; ++j) {
                int d = sd + j;
                Vt[d * 40 + (sk ^ (((d >> 3) & 3) << 3))] = vv.s[j];
            }
        }
        __syncthreads();

        if (t < ntile) {
            int s0 = t * 32;
            bf16x8 kf[4];
#pragma unroll
            for (int c = 0; c < 4; ++c)
                kf[c] = *(const bf16x8*)(Kg + (size_t)(s0 + q) * 2304 + c * 16 + hh * 8);

            f32x16 sacc = (f32x16)0.f;
#pragma unroll
            for (int c = 0; c < 4; ++c)
                sacc = __builtin_amdgcn_mfma_f32_32x32x16_bf16(kf[c], qf[c], sacc, 0, 0, 0);

            float p[16];
            float tm = -3e38f;
#pragma unroll
            for (int r = 0; r < 16; ++r) {
                p[r] = sacc[r] * SC;
                tm = fmaxf(tm, p[r]);
            }
            tm = fmaxf(tm, __shfl_xor(tm, 32));
            if (!__all(tm <= m + 8.f)) {
                float mn = fmaxf(m, tm);
                float al = __builtin_amdgcn_exp2f(m - mn);
                lsum *= al;
#pragma unroll
                for (int r = 0; r < 16; ++r) { o0[r] *= al; o1[r] *= al; }
                m = mn;
            }
#pragma unroll
            for (int r = 0; r < 16; ++r) {
                p[r] = __builtin_amdgcn_exp2f(p[r] - m);
                lsum += p[r];
            }

            unsigned a0 = cvt_pk_bf16(p[0], p[1]);
            unsigned a1 = cvt_pk_bf16(p[2], p[3]);
            unsigned b0 = cvt_pk_bf16(p[4], p[5]);
            unsigned b1 = cvt_pk_bf16(p[6], p[7]);
            asm("v_permlane32_swap_b32 %0, %1" : "+v"(a0), "+v"(b0));
            asm("v_permlane32_swap_b32 %0, %1" : "+v"(a1), "+v"(b1));
            unsigned c0 = cvt_pk_bf16(p[8], p[9]);
            unsigned c1 = cvt_pk_bf16(p[10], p[11]);
            unsigned d0 = cvt_pk_bf16(p[12], p[13]);
            unsigned d1 = cvt_pk_bf16(p[14], p[15]);
            asm("v_permlane32_swap_b32 %0, %1" : "+v"(c0), "+v"(d0));
            asm("v_permlane32_swap_b32 %0, %1" : "+v"(c1), "+v"(d1));
            union { unsigned u[4]; bf16x8 v; } pf0, pf1;
            pf0.u[0] = a0; pf0.u[1] = a1; pf0.u[2] = b0; pf0.u[3] = b1;
            pf1.u[0] = c0; pf1.u[1] = c1; pf1.u[2] = d0; pf1.u[3] = d1;

            {
                int d = q;
                int sw = (d >> 3) & 3;
                bf16x8 va0 = *(const bf16x8*)&Vt[d * 40 + ((0 + hh) ^ sw) * 8];
                bf16x8 va1 = *(const bf16x8*)&Vt[d * 40 + ((2 + hh) ^ sw) * 8];
                o0 = __builtin_amdgcn_mfma_f32_32x32x16_bf16(va0, pf0.v, o0, 0, 0, 0);
                o0 = __builtin_amdgcn_mfma_f32_32x32x16_bf16(va1, pf1.v, o0, 0, 0, 0);
            }
            {
                int d = 32 + q;
                int sw = (d >> 3) & 3;
                bf16x8 va0 = *(const bf16x8*)&Vt[d * 40 + ((0 + hh) ^ sw) * 8];
                bf16x8 va1 = *(const bf16x8*)&Vt[d * 40 + ((2 + hh) ^ sw) * 8];
                o1 = __builtin_amdgcn_mfma_f32_32x32x16_bf16(va0, pf0.v, o1, 0, 0, 0);
                o1 = __builtin_amdgcn_mfma_f32_32x32x16_bf16(va1, pf1.v, o1, 0, 0, 0);
            }
        }
        __syncthreads();
    }

    lsum += __shfl_xor(lsum, 32);
    float inv = 1.f / lsum;
    unsigned short* yp = y + (size_t)(bt * 320 + q0 + q) * 768 + h * 64;
#pragma unroll
    for (int r = 0; r < 16; r += 2) {
        int dr = (r & 3) + 8 * (r >> 2) + 4 * hh;
        *(unsigned*)(yp + dr) =
            (unsigned)f2bf(o0[r] * inv) | ((unsigned)f2bf(o0[r + 1] * inv) << 16);
        *(unsigned*)(yp + 32 + dr) =
            (unsigned)f2bf(o1[r] * inv) | ((unsigned)f2bf(o1[r + 1] * inv) << 16);
    }
}

// ---------------- launcher ----------------
extern "C" void kernel_launch(void* const* d_in, const int* in_sizes, int n_in,
                              void* d_out, int out_size, void* d_ws, size_t ws_size,
                              hipStream_t stream) {
    const float* x     = (const float*)d_in[0];
    const float* qkv_w = (const float*)d_in[1];
    const float* qkv_b = (const float*)d_in[2];
    const float* out_w = (const float*)d_in[3];
    const float* out_b = (const float*)d_in[4];

    const int M = 40960;  // B*T*S = 4*32*320
    unsigned short* xb  = (unsigned short*)d_ws;
    unsigned short* w1t = xb + (size_t)M * 768;           // [2304][768]
    unsigned short* w2t = w1t + (size_t)2304 * 768;       // [768][768]
    unsigned short* qkv = w2t + (size_t)768 * 768;        // [M][2304]
    unsigned short* yb  = qkv + (size_t)M * 2304;         // [M][768]

    k_convert<<<(M * 768 / 8 + 255) / 256, 256, 0, stream>>>(x, xb, M * 768 / 8);
    k_transpose<<<dim3(2304 / 32, 768 / 32), dim3(32, 8), 0, stream>>>(qkv_w, w1t, 768, 2304);
    k_transpose<<<dim3(768 / 32, 768 / 32), dim3(32, 8), 0, stream>>>(out_w, w2t, 768, 768);

    k_gemm256<true><<<(M / 256) * (2304 / 256), 512, 0, stream>>>(xb, w1t, qkv_b, (void*)qkv, M, 2304, 768);
    k_attn2<<<128 * 12, 640, 0, stream>>>(qkv, yb);
    k_gemm256<false><<<(M / 256) * (768 / 256), 512, 0, stream>>>(yb, w2t, out_b, d_out, M, 768, 768);
}

// Round 6
// 381.876 us; speedup vs baseline: 1.8260x; 1.1487x over previous
//
#include <hip/hip_runtime.h>

typedef __attribute__((ext_vector_type(8))) short bf16x8;
typedef __attribute__((ext_vector_type(4))) float f32x4;
typedef __attribute__((ext_vector_type(16))) float f32x16;
typedef __attribute__((address_space(1))) void gvoid_t;
typedef __attribute__((address_space(3))) void lvoid_t;

#define DEVI __device__ __forceinline__

DEVI unsigned short f2bf(float f) {
    unsigned int u = __builtin_bit_cast(unsigned int, f);
    u += 0x7fffu + ((u >> 16) & 1u);   // RNE
    return (unsigned short)(u >> 16);
}

DEVI unsigned cvt_pk_bf16(float a, float b) {
    unsigned r;
    asm("v_cvt_pk_bf16_f32 %0, %1, %2" : "=v"(r) : "v"(a), "v"(b));
    return r;
}

DEVI f32x4 mfma16(bf16x8 a, bf16x8 b, f32x4 c) {
    return __builtin_amdgcn_mfma_f32_16x16x32_bf16(a, b, c, 0, 0, 0);
}

// ---------------- fp32 -> bf16 elementwise (8 elems/thread) ----------------
__global__ void k_convert(const float* __restrict__ in, unsigned short* __restrict__ out, int n8) {
    int i = blockIdx.x * 256 + threadIdx.x;
    if (i >= n8) return;
    const float4* p = (const float4*)in + (size_t)i * 2;
    float4 a = p[0], b = p[1];
    uint4 o;
    o.x = f2bf(a.x) | ((unsigned)f2bf(a.y) << 16);
    o.y = f2bf(a.z) | ((unsigned)f2bf(a.w) << 16);
    o.z = f2bf(b.x) | ((unsigned)f2bf(b.y) << 16);
    o.w = f2bf(b.z) | ((unsigned)f2bf(b.w) << 16);
    *((uint4*)out + i) = o;
}

// ---------------- transpose+convert: w[K][N] f32 -> wt[N][K] bf16 ----------------
__global__ void k_transpose(const float* __restrict__ w, unsigned short* __restrict__ wt, int K, int N) {
    __shared__ float tile[32][33];
    int n0 = blockIdx.x * 32, k0 = blockIdx.y * 32;
    int tx = threadIdx.x, ty = threadIdx.y;
#pragma unroll
    for (int r = 0; r < 32; r += 8)
        tile[ty + r][tx] = w[(size_t)(k0 + ty + r) * N + n0 + tx];
    __syncthreads();
#pragma unroll
    for (int r = 0; r < 32; r += 8)
        wt[(size_t)(n0 + ty + r) * K + k0 + tx] = f2bf(tile[tx][ty + r]);
}

// ---------------- 256x256 8-phase bf16 GEMM: C[M,N] = A[M,K]*Bt[N,K]^T + bias --------
template <bool OUT_BF16>
__global__ __launch_bounds__(512, 2) void k_gemm256(const unsigned short* __restrict__ A,
                                                    const unsigned short* __restrict__ Bt,
                                                    const float* __restrict__ bias,
                                                    void* __restrict__ out,
                                                    int M, int N, int K) {
    __shared__ unsigned short smem[65536];   // A[2][256][64] @0, B[2][256][64] @32768

    const int tid = threadIdx.x;
    const int nwg = gridDim.x, bid = blockIdx.x;
    const int q8 = nwg >> 3, r8 = nwg & 7;
    const int xcd = bid & 7, lid = bid >> 3;
    const int swz = ((xcd < r8) ? xcd * (q8 + 1) : r8 * (q8 + 1) + (xcd - r8) * q8) + lid;
    const int ntn = N >> 8;
    const int bm = swz / ntn, bn = swz % ntn;

    const int lane = tid & 63, wid = tid >> 6;
    const int wr = wid >> 2, wc = wid & 3;
    const int lr = lane & 15, lg = lane >> 4;
    const int cswz = (lr & 7) << 3;
    const int col0 = (lg * 8) ^ cswz;

    const int NT = K >> 6;

    const int srowl = tid >> 3;
    const int scole = ((tid & 7) ^ (srowl & 7)) << 3;
    const unsigned short* aSrc = A  + (size_t)(bm * 256 + srowl) * K + scole;
    const unsigned short* bSrc = Bt + (size_t)(bn * 256 + srowl) * K + scole;

#define STG(matOff, srcBase, qq, koff, bufw)                                              \
    __builtin_amdgcn_global_load_lds((gvoid_t*)((srcBase) + (size_t)(qq) * 64 * K + (koff)), \
        (lvoid_t*)(smem + (matOff) + (bufw) * 16384 + (qq) * 4096 + tid * 8), 16, 0, 0)

    f32x4 acc[8][4];
#pragma unroll
    for (int i = 0; i < 8; ++i)
#pragma unroll
        for (int j = 0; j < 4; ++j) acc[i][j] = (f32x4){0.f, 0.f, 0.f, 0.f};

    {
        const int k1 = (NT > 1) ? 64 : 0;
        STG(0, aSrc, 0, 0, 0); STG(0, aSrc, 1, 0, 0); STG(0, aSrc, 2, 0, 0); STG(0, aSrc, 3, 0, 0);
        STG(32768, bSrc, 0, 0, 0); STG(32768, bSrc, 1, 0, 0); STG(32768, bSrc, 2, 0, 0); STG(32768, bSrc, 3, 0, 0);
        STG(0, aSrc, 0, k1, 1); STG(0, aSrc, 2, k1, 1);
        asm volatile("s_waitcnt vmcnt(2)" ::: "memory");
        __builtin_amdgcn_s_barrier();
    }

#pragma unroll 1
    for (int t = 0; t < NT; ++t) {
        const int bufR = t & 1, bufW = bufR ^ 1;
        const int ko1 = (t + 1 < NT) ? (t + 1) * 64 : 0;
        const int ko2 = (t + 2 < NT) ? (t + 2) * 64 : 0;
        const unsigned short* abuf = smem + bufR * 16384;
        const unsigned short* bbuf = smem + 32768 + bufR * 16384;
        bf16x8 af[4][2], bfr[2][2];

        // ---- phase 0: (mh=0, nh=0) ----
#pragma unroll
        for (int mf = 0; mf < 4; ++mf)
#pragma unroll
            for (int kk = 0; kk < 2; ++kk)
                af[mf][kk] = *(const bf16x8*)(abuf + (wr * 128 + mf * 16 + lr) * 64 + (col0 ^ (kk * 32)));
#pragma unroll
        for (int j = 0; j < 2; ++j)
#pragma unroll
            for (int kk = 0; kk < 2; ++kk)
                bfr[j][kk] = *(const bf16x8*)(bbuf + (wc * 64 + j * 16 + lr) * 64 + (col0 ^ (kk * 32)));
        STG(32768, bSrc, 0, ko1, bufW); STG(32768, bSrc, 1, ko1, bufW);
        __builtin_amdgcn_s_barrier();
        asm volatile("s_waitcnt lgkmcnt(0)" ::: "memory");
        __builtin_amdgcn_sched_barrier(0);
        __builtin_amdgcn_s_setprio(1);
#pragma unroll
        for (int mf = 0; mf < 4; ++mf)
#pragma unroll
            for (int j = 0; j < 2; ++j)
#pragma unroll
                for (int kk = 0; kk < 2; ++kk)
                    acc[mf][j] = mfma16(af[mf][kk], bfr[j][kk], acc[mf][j]);
        __builtin_amdgcn_s_setprio(0);
        __builtin_amdgcn_s_barrier();

        // ---- phase 1: (mh=0, nh=1) ----
#pragma unroll
        for (int j = 0; j < 2; ++j)
#pragma unroll
            for (int kk = 0; kk < 2; ++kk)
                bfr[j][kk] = *(const bf16x8*)(bbuf + (wc * 64 + (2 + j) * 16 + lr) * 64 + (col0 ^ (kk * 32)));
        STG(32768, bSrc, 2, ko1, bufW); STG(32768, bSrc, 3, ko1, bufW);
        __builtin_amdgcn_s_barrier();
        asm volatile("s_waitcnt lgkmcnt(0)" ::: "memory");
        __builtin_amdgcn_sched_barrier(0);
        __builtin_amdgcn_s_setprio(1);
#pragma unroll
        for (int mf = 0; mf < 4; ++mf)
#pragma unroll
            for (int j = 0; j < 2; ++j)
#pragma unroll
                for (int kk = 0; kk < 2; ++kk)
                    acc[mf][2 + j] = mfma16(af[mf][kk], bfr[j][kk], acc[mf][2 + j]);
        __builtin_amdgcn_s_setprio(0);
        __builtin_amdgcn_s_barrier();

        // ---- phase 2: (mh=1, nh=1) ----
#pragma unroll
        for (int mf = 0; mf < 4; ++mf)
#pragma unroll
            for (int kk = 0; kk < 2; ++kk)
                af[mf][kk] = *(const bf16x8*)(abuf + (wr * 128 + 64 + mf * 16 + lr) * 64 + (col0 ^ (kk * 32)));
        STG(0, aSrc, 1, ko1, bufW); STG(0, aSrc, 3, ko1, bufW);
        __builtin_amdgcn_s_barrier();
        asm volatile("s_waitcnt lgkmcnt(0)" ::: "memory");
        __builtin_amdgcn_sched_barrier(0);
        __builtin_amdgcn_s_setprio(1);
#pragma unroll
        for (int mf = 0; mf < 4; ++mf)
#pragma unroll
            for (int j = 0; j < 2; ++j)
#pragma unroll
                for (int kk = 0; kk < 2; ++kk)
                    acc[4 + mf][2 + j] = mfma16(af[mf][kk], bfr[j][kk], acc[4 + mf][2 + j]);
        __builtin_amdgcn_s_setprio(0);
        __builtin_amdgcn_s_barrier();

        // ---- phase 3: (mh=1, nh=0); stages t+2 A-L0/L2 into bufR ----
#pragma unroll
        for (int j = 0; j < 2; ++j)
#pragma unroll
            for (int kk = 0; kk < 2; ++kk)
                bfr[j][kk] = *(const bf16x8*)(bbuf + (wc * 64 + j * 16 + lr) * 64 + (col0 ^ (kk * 32)));
        STG(0, aSrc, 0, ko2, bufR); STG(0, aSrc, 2, ko2, bufR);
        __builtin_amdgcn_s_barrier();
        asm volatile("s_waitcnt lgkmcnt(0)" ::: "memory");
        __builtin_amdgcn_sched_barrier(0);
        __builtin_amdgcn_s_setprio(1);
#pragma unroll
        for (int mf = 0; mf < 4; ++mf)
#pragma unroll
            for (int j = 0; j < 2; ++j)
#pragma unroll
                for (int kk = 0; kk < 2; ++kk)
                    acc[4 + mf][j] = mfma16(af[mf][kk], bfr[j][kk], acc[4 + mf][j]);
        __builtin_amdgcn_s_setprio(0);
        asm volatile("s_waitcnt vmcnt(2)" ::: "memory");
        __builtin_amdgcn_s_barrier();
    }
#undef STG

#pragma unroll
    for (int mf = 0; mf < 8; ++mf)
#pragma unroll
        for (int nf = 0; nf < 4; ++nf) {
            int col = bn * 256 + wc * 64 + nf * 16 + lr;
            float bv = bias[col];
#pragma unroll
            for (int i = 0; i < 4; ++i) {
                int row = bm * 256 + wr * 128 + mf * 16 + lg * 4 + i;
                float v = acc[mf][nf][i] + bv;
                if (OUT_BF16)
                    ((unsigned short*)out)[(size_t)row * N + col] = f2bf(v);
                else
                    ((float*)out)[(size_t)row * N + col] = v;
            }
        }
}

// ---------------- fused flash attention v3: full-V LDS, barrier-free tile loop -------
// Block = (bt,h): 10 waves, wave w owns q-tile w. All of V^T (10 tiles x 64 x 40,
// swizzled exactly as v2) staged ONCE; single __syncthreads; waves then run
// independently. Latent waves (w<2) process 2 tiles and retire.
__global__ __launch_bounds__(640) void k_attn3(const unsigned short* __restrict__ qkv,
                                               unsigned short* __restrict__ y) {
    int bt = blockIdx.x / 12, h = blockIdx.x % 12;
    const unsigned short* Qg = qkv + (size_t)bt * 320 * 2304 + h * 64;
    const unsigned short* Kg = Qg + 768;
    const unsigned short* Vg = Qg + 1536;

    __shared__ unsigned short Vt[10 * 64 * 40];   // [t][d][k'], per-tile layout == v2

    int tid = threadIdx.x, w = tid >> 6, l = tid & 63;
    int q = l & 31, hh = l >> 5;
    int q0 = w * 32;
    int ntile = (w < 2) ? 2 : 10;

    // one-time staging: thread -> global V row k = tid>>1, d-half (tid&1)*32
    {
        int k = tid >> 1;
        int tt = k >> 5, sk = k & 31;
        int d0 = (tid & 1) * 32;
        const unsigned short* src = Vg + (size_t)k * 2304 + d0;
#pragma unroll
        for (int c = 0; c < 4; ++c) {
            union { uint4 u; unsigned short s[8]; } vv;
            vv.u = *(const uint4*)(src + c * 8);
#pragma unroll
            for (int j = 0; j < 8; ++j) {
                int d = d0 + c * 8 + j;
                Vt[(tt * 64 + d) * 40 + (sk ^ (((d >> 3) & 3) << 3))] = vv.s[j];
            }
        }
    }

    bf16x8 qf[4];
#pragma unroll
    for (int c = 0; c < 4; ++c)
        qf[c] = *(const bf16x8*)(Qg + (size_t)(q0 + q) * 2304 + c * 16 + hh * 8);

    f32x16 o0 = (f32x16)0.f, o1 = (f32x16)0.f;
    float m = -3e38f, lsum = 0.f;
    const float SC = 0.125f * 1.44269504089f;

    __syncthreads();   // Vt ready; no further block syncs

    for (int t = 0; t < ntile; ++t) {
        int s0 = t * 32;
        bf16x8 kf[4];
#pragma unroll
        for (int c = 0; c < 4; ++c)
            kf[c] = *(const bf16x8*)(Kg + (size_t)(s0 + q) * 2304 + c * 16 + hh * 8);

        f32x16 sacc = (f32x16)0.f;
#pragma unroll
        for (int c = 0; c < 4; ++c)
            sacc = __builtin_amdgcn_mfma_f32_32x32x16_bf16(kf[c], qf[c], sacc, 0, 0, 0);

        float p[16];
#pragma unroll
        for (int r = 0; r < 16; ++r) p[r] = sacc[r] * SC;
        // tree max (depth 4)
        float tm = fmaxf(
            fmaxf(fmaxf(fmaxf(p[0], p[1]), fmaxf(p[2], p[3])),
                  fmaxf(fmaxf(p[4], p[5]), fmaxf(p[6], p[7]))),
            fmaxf(fmaxf(fmaxf(p[8], p[9]), fmaxf(p[10], p[11])),
                  fmaxf(fmaxf(p[12], p[13]), fmaxf(p[14], p[15]))));
        tm = fmaxf(tm, __shfl_xor(tm, 32));
        if (!__all(tm <= m + 8.f)) {
            float mn = fmaxf(m, tm);
            float al = __builtin_amdgcn_exp2f(m - mn);
            lsum *= al;
#pragma unroll
            for (int r = 0; r < 16; ++r) { o0[r] *= al; o1[r] *= al; }
            m = mn;
        }
#pragma unroll
        for (int r = 0; r < 16; ++r) p[r] = __builtin_amdgcn_exp2f(p[r] - m);
        // tree sum
        float rs =
            ((p[0] + p[1]) + (p[2] + p[3])) + ((p[4] + p[5]) + (p[6] + p[7])) +
            (((p[8] + p[9]) + (p[10] + p[11])) + ((p[12] + p[13]) + (p[14] + p[15])));
        lsum += rs;

        unsigned a0 = cvt_pk_bf16(p[0], p[1]);
        unsigned a1 = cvt_pk_bf16(p[2], p[3]);
        unsigned b0 = cvt_pk_bf16(p[4], p[5]);
        unsigned b1 = cvt_pk_bf16(p[6], p[7]);
        asm("v_permlane32_swap_b32 %0, %1" : "+v"(a0), "+v"(b0));
        asm("v_permlane32_swap_b32 %0, %1" : "+v"(a1), "+v"(b1));
        unsigned c0 = cvt_pk_bf16(p[8], p[9]);
        unsigned c1 = cvt_pk_bf16(p[10], p[11]);
        unsigned d0 = cvt_pk_bf16(p[12], p[13]);
        unsigned d1 = cvt_pk_bf16(p[14], p[15]);
        asm("v_permlane32_swap_b32 %0, %1" : "+v"(c0), "+v"(d0));
        asm("v_permlane32_swap_b32 %0, %1" : "+v"(c1), "+v"(d1));
        union { unsigned u[4]; bf16x8 v; } pf0, pf1;
        pf0.u[0] = a0; pf0.u[1] = a1; pf0.u[2] = b0; pf0.u[3] = b1;
        pf1.u[0] = c0; pf1.u[1] = c1; pf1.u[2] = d0; pf1.u[3] = d1;

        const unsigned short* vt = Vt + t * 2560;
        {
            int d = q;
            int sw = (d >> 3) & 3;
            bf16x8 va0 = *(const bf16x8*)&vt[d * 40 + ((0 + hh) ^ sw) * 8];
            bf16x8 va1 = *(const bf16x8*)&vt[d * 40 + ((2 + hh) ^ sw) * 8];
            o0 = __builtin_amdgcn_mfma_f32_32x32x16_bf16(va0, pf0.v, o0, 0, 0, 0);
            o0 = __builtin_amdgcn_mfma_f32_32x32x16_bf16(va1, pf1.v, o0, 0, 0, 0);
        }
        {
            int d = 32 + q;
            int sw = (d >> 3) & 3;
            bf16x8 va0 = *(const bf16x8*)&vt[d * 40 + ((0 + hh) ^ sw) * 8];
            bf16x8 va1 = *(const bf16x8*)&vt[d * 40 + ((2 + hh) ^ sw) * 8];
            o1 = __builtin_amdgcn_mfma_f32_32x32x16_bf16(va0, pf0.v, o1, 0, 0, 0);
            o1 = __builtin_amdgcn_mfma_f32_32x32x16_bf16(va1, pf1.v, o1, 0, 0, 0);
        }
    }

    lsum += __shfl_xor(lsum, 32);
    float inv = 1.f / lsum;
    unsigned short* yp = y + (size_t)(bt * 320 + q0 + q) * 768 + h * 64;
#pragma unroll
    for (int r = 0; r < 16; r += 2) {
        int dr = (r & 3) + 8 * (r >> 2) + 4 * hh;
        *(unsigned*)(yp + dr) =
            (unsigned)f2bf(o0[r] * inv) | ((unsigned)f2bf(o0[r + 1] * inv) << 16);
        *(unsigned*)(yp + 32 + dr) =
            (unsigned)f2bf(o1[r] * inv) | ((unsigned)f2bf(o1[r + 1] * inv) << 16);
    }
}

// ---------------- launcher ----------------
extern "C" void kernel_launch(void* const* d_in, const int* in_sizes, int n_in,
                              void* d_out, int out_size, void* d_ws, size_t ws_size,
                              hipStream_t stream) {
    const float* x     = (const float*)d_in[0];
    const float* qkv_w = (const float*)d_in[1];
    const float* qkv_b = (const float*)d_in[2];
    const float* out_w = (const float*)d_in[3];
    const float* out_b = (const float*)d_in[4];

    const int M = 40960;  // B*T*S = 4*32*320
    unsigned short* xb  = (unsigned short*)d_ws;
    unsigned short* w1t = xb + (size_t)M * 768;           // [2304][768]
    unsigned short* w2t = w1t + (size_t)2304 * 768;       // [768][768]
    unsigned short* qkv = w2t + (size_t)768 * 768;        // [M][2304]
    unsigned short* yb  = qkv + (size_t)M * 2304;         // [M][768]

    k_convert<<<(M * 768 / 8 + 255) / 256, 256, 0, stream>>>(x, xb, M * 768 / 8);
    k_transpose<<<dim3(2304 / 32, 768 / 32), dim3(32, 8), 0, stream>>>(qkv_w, w1t, 768, 2304);
    k_transpose<<<dim3(768 / 32, 768 / 32), dim3(32, 8), 0, stream>>>(out_w, w2t, 768, 768);

    k_gemm256<true><<<(M / 256) * (2304 / 256), 512, 0, stream>>>(xb, w1t, qkv_b, (void*)qkv, M, 2304, 768);
    k_attn3<<<128 * 12, 640, 0, stream>>>(qkv, yb);
    k_gemm256<false><<<(M / 256) * (768 / 256), 512, 0, stream>>>(yb, w2t, out_b, d_out, M, 768, 768);
}

// Round 7
// 378.605 us; speedup vs baseline: 1.8418x; 1.0086x over previous
//
#include <hip/hip_runtime.h>

typedef __attribute__((ext_vector_type(8))) short bf16x8;
typedef __attribute__((ext_vector_type(4))) float f32x4;
typedef __attribute__((ext_vector_type(16))) float f32x16;
typedef __attribute__((address_space(1))) void gvoid_t;
typedef __attribute__((address_space(3))) void lvoid_t;

#define DEVI __device__ __forceinline__

DEVI unsigned short f2bf(float f) {
    unsigned int u = __builtin_bit_cast(unsigned int, f);
    u += 0x7fffu + ((u >> 16) & 1u);   // RNE
    return (unsigned short)(u >> 16);
}

DEVI unsigned cvt_pk_bf16(float a, float b) {
    unsigned r;
    asm("v_cvt_pk_bf16_f32 %0, %1, %2" : "=v"(r) : "v"(a), "v"(b));
    return r;
}

DEVI f32x4 mfma16(bf16x8 a, bf16x8 b, f32x4 c) {
    return __builtin_amdgcn_mfma_f32_16x16x32_bf16(a, b, c, 0, 0, 0);
}

// ---------------- fp32 -> bf16 elementwise (8 elems/thread) ----------------
__global__ void k_convert(const float* __restrict__ in, unsigned short* __restrict__ out, int n8) {
    int i = blockIdx.x * 256 + threadIdx.x;
    if (i >= n8) return;
    const float4* p = (const float4*)in + (size_t)i * 2;
    float4 a = p[0], b = p[1];
    uint4 o;
    o.x = f2bf(a.x) | ((unsigned)f2bf(a.y) << 16);
    o.y = f2bf(a.z) | ((unsigned)f2bf(a.w) << 16);
    o.z = f2bf(b.x) | ((unsigned)f2bf(b.y) << 16);
    o.w = f2bf(b.z) | ((unsigned)f2bf(b.w) << 16);
    *((uint4*)out + i) = o;
}

// ---------------- transpose+convert: w[K][N] f32 -> wt[N][K] bf16 ----------------
__global__ void k_transpose(const float* __restrict__ w, unsigned short* __restrict__ wt, int K, int N) {
    __shared__ float tile[32][33];
    int n0 = blockIdx.x * 32, k0 = blockIdx.y * 32;
    int tx = threadIdx.x, ty = threadIdx.y;
#pragma unroll
    for (int r = 0; r < 32; r += 8)
        tile[ty + r][tx] = w[(size_t)(k0 + ty + r) * N + n0 + tx];
    __syncthreads();
#pragma unroll
    for (int r = 0; r < 32; r += 8)
        wt[(size_t)(n0 + ty + r) * K + k0 + tx] = f2bf(tile[tx][ty + r]);
}

// ---------------- 256x256 8-phase bf16 GEMM: C[M,N] = A[M,K]*Bt[N,K]^T + bias --------
// 512 thr = 8 waves (2M x 4N); wave tile 128x64; BK=64 double-buffered.
// B-fragments for both nh halves held in regs (b01/b23) -> no phase-3 ds_read.
// Epilogue staged through LDS for coalesced dwordx4 stores.
template <bool OUT_BF16>
__global__ __launch_bounds__(512, 2) void k_gemm256(const unsigned short* __restrict__ A,
                                                    const unsigned short* __restrict__ Bt,
                                                    const float* __restrict__ bias,
                                                    void* __restrict__ out,
                                                    int M, int N, int K) {
    __shared__ unsigned short smem[65536];   // A[2][256][64] @0, B[2][256][64] @32768

    const int tid = threadIdx.x;
    const int nwg = gridDim.x, bid = blockIdx.x;
    const int q8 = nwg >> 3, r8 = nwg & 7;
    const int xcd = bid & 7, lid = bid >> 3;
    const int swz = ((xcd < r8) ? xcd * (q8 + 1) : r8 * (q8 + 1) + (xcd - r8) * q8) + lid;
    const int ntn = N >> 8;
    const int bm = swz / ntn, bn = swz % ntn;

    const int lane = tid & 63, wid = tid >> 6;
    const int wr = wid >> 2, wc = wid & 3;
    const int lr = lane & 15, lg = lane >> 4;
    const int cswz = (lr & 7) << 3;
    const int col0 = (lg * 8) ^ cswz;

    const int NT = K >> 6;

    const int srowl = tid >> 3;
    const int scole = ((tid & 7) ^ (srowl & 7)) << 3;
    const unsigned short* aSrc = A  + (size_t)(bm * 256 + srowl) * K + scole;
    const unsigned short* bSrc = Bt + (size_t)(bn * 256 + srowl) * K + scole;

#define STG(matOff, srcBase, qq, koff, bufw)                                              \
    __builtin_amdgcn_global_load_lds((gvoid_t*)((srcBase) + (size_t)(qq) * 64 * K + (koff)), \
        (lvoid_t*)(smem + (matOff) + (bufw) * 16384 + (qq) * 4096 + tid * 8), 16, 0, 0)

    f32x4 acc[8][4];
#pragma unroll
    for (int i = 0; i < 8; ++i)
#pragma unroll
        for (int j = 0; j < 4; ++j) acc[i][j] = (f32x4){0.f, 0.f, 0.f, 0.f};

    {
        const int k1 = (NT > 1) ? 64 : 0;
        STG(0, aSrc, 0, 0, 0); STG(0, aSrc, 1, 0, 0); STG(0, aSrc, 2, 0, 0); STG(0, aSrc, 3, 0, 0);
        STG(32768, bSrc, 0, 0, 0); STG(32768, bSrc, 1, 0, 0); STG(32768, bSrc, 2, 0, 0); STG(32768, bSrc, 3, 0, 0);
        STG(0, aSrc, 0, k1, 1); STG(0, aSrc, 2, k1, 1);
        asm volatile("s_waitcnt vmcnt(2)" ::: "memory");
        __builtin_amdgcn_s_barrier();
    }

#pragma unroll 1
    for (int t = 0; t < NT; ++t) {
        const int bufR = t & 1, bufW = bufR ^ 1;
        const int ko1 = (t + 1 < NT) ? (t + 1) * 64 : 0;
        const int ko2 = (t + 2 < NT) ? (t + 2) * 64 : 0;
        const unsigned short* abuf = smem + bufR * 16384;
        const unsigned short* bbuf = smem + 32768 + bufR * 16384;
        bf16x8 af[4][2], b01[2][2], b23[2][2];

        // ---- phase 0: (mh=0, nh=0) ----
#pragma unroll
        for (int mf = 0; mf < 4; ++mf)
#pragma unroll
            for (int kk = 0; kk < 2; ++kk)
                af[mf][kk] = *(const bf16x8*)(abuf + (wr * 128 + mf * 16 + lr) * 64 + (col0 ^ (kk * 32)));
#pragma unroll
        for (int j = 0; j < 2; ++j)
#pragma unroll
            for (int kk = 0; kk < 2; ++kk)
                b01[j][kk] = *(const bf16x8*)(bbuf + (wc * 64 + j * 16 + lr) * 64 + (col0 ^ (kk * 32)));
        STG(32768, bSrc, 0, ko1, bufW); STG(32768, bSrc, 1, ko1, bufW);
        __builtin_amdgcn_s_barrier();
        asm volatile("s_waitcnt lgkmcnt(0)" ::: "memory");
        __builtin_amdgcn_sched_barrier(0);
        __builtin_amdgcn_s_setprio(1);
#pragma unroll
        for (int mf = 0; mf < 4; ++mf)
#pragma unroll
            for (int j = 0; j < 2; ++j)
#pragma unroll
                for (int kk = 0; kk < 2; ++kk)
                    acc[mf][j] = mfma16(af[mf][kk], b01[j][kk], acc[mf][j]);
        __builtin_amdgcn_s_setprio(0);
        __builtin_amdgcn_s_barrier();

        // ---- phase 1: (mh=0, nh=1) ----
#pragma unroll
        for (int j = 0; j < 2; ++j)
#pragma unroll
            for (int kk = 0; kk < 2; ++kk)
                b23[j][kk] = *(const bf16x8*)(bbuf + (wc * 64 + (2 + j) * 16 + lr) * 64 + (col0 ^ (kk * 32)));
        STG(32768, bSrc, 2, ko1, bufW); STG(32768, bSrc, 3, ko1, bufW);
        __builtin_amdgcn_s_barrier();
        asm volatile("s_waitcnt lgkmcnt(0)" ::: "memory");
        __builtin_amdgcn_sched_barrier(0);
        __builtin_amdgcn_s_setprio(1);
#pragma unroll
        for (int mf = 0; mf < 4; ++mf)
#pragma unroll
            for (int j = 0; j < 2; ++j)
#pragma unroll
                for (int kk = 0; kk < 2; ++kk)
                    acc[mf][2 + j] = mfma16(af[mf][kk], b23[j][kk], acc[mf][2 + j]);
        __builtin_amdgcn_s_setprio(0);
        __builtin_amdgcn_s_barrier();

        // ---- phase 2: (mh=1, nh=1) ----
#pragma unroll
        for (int mf = 0; mf < 4; ++mf)
#pragma unroll
            for (int kk = 0; kk < 2; ++kk)
                af[mf][kk] = *(const bf16x8*)(abuf + (wr * 128 + 64 + mf * 16 + lr) * 64 + (col0 ^ (kk * 32)));
        STG(0, aSrc, 1, ko1, bufW); STG(0, aSrc, 3, ko1, bufW);
        __builtin_amdgcn_s_barrier();
        asm volatile("s_waitcnt lgkmcnt(0)" ::: "memory");
        __builtin_amdgcn_sched_barrier(0);
        __builtin_amdgcn_s_setprio(1);
#pragma unroll
        for (int mf = 0; mf < 4; ++mf)
#pragma unroll
            for (int j = 0; j < 2; ++j)
#pragma unroll
                for (int kk = 0; kk < 2; ++kk)
                    acc[4 + mf][2 + j] = mfma16(af[mf][kk], b23[j][kk], acc[4 + mf][2 + j]);
        __builtin_amdgcn_s_setprio(0);
        __builtin_amdgcn_s_barrier();

        // ---- phase 3: (mh=1, nh=0); b01 reused from regs; stages t+2 A-L0/L2 into bufR ----
        STG(0, aSrc, 0, ko2, bufR); STG(0, aSrc, 2, ko2, bufR);
        __builtin_amdgcn_s_setprio(1);
#pragma unroll
        for (int mf = 0; mf < 4; ++mf)
#pragma unroll
            for (int j = 0; j < 2; ++j)
#pragma unroll
                for (int kk = 0; kk < 2; ++kk)
                    acc[4 + mf][j] = mfma16(af[mf][kk], b01[j][kk], acc[4 + mf][j]);
        __builtin_amdgcn_s_setprio(0);
        asm volatile("s_waitcnt vmcnt(2)" ::: "memory");
        __builtin_amdgcn_s_barrier();
    }
#undef STG

    // ---- epilogue: LDS-staged coalesced stores (per-wave 16KB region of smem) ----
    asm volatile("s_waitcnt vmcnt(0)" ::: "memory");   // drain stray prefetches into smem
    float bv[4];
#pragma unroll
    for (int nf = 0; nf < 4; ++nf)
        bv[nf] = bias[bn * 256 + wc * 64 + nf * 16 + lr];

    if (OUT_BF16) {
        unsigned short* ebuf = smem + wid * 8192;      // 64 rows x stride 72 bf16 (9216B)
#pragma unroll
        for (int h = 0; h < 2; ++h) {
#pragma unroll
            for (int mf4 = 0; mf4 < 4; ++mf4) {
                int mf = h * 4 + mf4;
#pragma unroll
                for (int nf = 0; nf < 4; ++nf)
#pragma unroll
                    for (int i = 0; i < 4; ++i)
                        ebuf[(mf4 * 16 + lg * 4 + i) * 72 + nf * 16 + lr] = f2bf(acc[mf][nf][i] + bv[nf]);
            }
            asm volatile("s_waitcnt lgkmcnt(0)" ::: "memory");
            __builtin_amdgcn_sched_barrier(0);
#pragma unroll
            for (int ps = 0; ps < 8; ++ps) {
                int rl = ps * 8 + (lane >> 3), ck = lane & 7;
                uint4 vv = *(const uint4*)&ebuf[rl * 72 + ck * 8];
                int grow = bm * 256 + wr * 128 + h * 64 + rl;
                int gcol = bn * 256 + wc * 64 + ck * 8;
                *(uint4*)&((unsigned short*)out)[(size_t)grow * N + gcol] = vv;
            }
            asm volatile("s_waitcnt lgkmcnt(0)" ::: "memory");
            __builtin_amdgcn_sched_barrier(0);
        }
    } else {
        float* ebuf = (float*)smem + wid * 4096;       // 32 rows x stride 68 f32 (8704B)
#pragma unroll
        for (int qq = 0; qq < 4; ++qq) {
#pragma unroll
            for (int m2 = 0; m2 < 2; ++m2) {
                int mf = qq * 2 + m2;
#pragma unroll
                for (int nf = 0; nf < 4; ++nf)
#pragma unroll
                    for (int i = 0; i < 4; ++i)
                        ebuf[(m2 * 16 + lg * 4 + i) * 68 + nf * 16 + lr] = acc[mf][nf][i] + bv[nf];
            }
            asm volatile("s_waitcnt lgkmcnt(0)" ::: "memory");
            __builtin_amdgcn_sched_barrier(0);
#pragma unroll
            for (int ps = 0; ps < 8; ++ps) {
                int rl = ps * 4 + (lane >> 4), ck = lane & 15;
                uint4 vv = *(const uint4*)&ebuf[rl * 68 + ck * 4];
                int grow = bm * 256 + wr * 128 + qq * 32 + rl;
                int gcol = bn * 256 + wc * 64 + ck * 4;
                *(uint4*)&((float*)out)[(size_t)grow * N + gcol] = vv;
            }
            asm volatile("s_waitcnt lgkmcnt(0)" ::: "memory");
            __builtin_amdgcn_sched_barrier(0);
        }
    }
}

// ---------------- fused flash attention v4: full-V LDS + pipelined K loads ----------
// Block = (bt,h): 10 waves, wave w owns q-tile w; latent waves (w<2) do 2 tiles.
// V^T staged once (swizzled); tile loop unrolled x2 with kfA/kfB ping-pong so the
// next tile's K global loads overlap current tile's softmax+PV.
__global__ __launch_bounds__(640) void k_attn4(const unsigned short* __restrict__ qkv,
                                               unsigned short* __restrict__ y) {
    int bt = blockIdx.x / 12, h = blockIdx.x % 12;
    const unsigned short* Qg = qkv + (size_t)bt * 320 * 2304 + h * 64;
    const unsigned short* Kg = Qg + 768;
    const unsigned short* Vg = Qg + 1536;

    __shared__ unsigned short Vt[10 * 64 * 40];   // [t][d][k'], swizzled per-tile

    int tid = threadIdx.x, w = tid >> 6, l = tid & 63;
    int q = l & 31, hh = l >> 5;
    int q0 = w * 32;
    int ntile = (w < 2) ? 2 : 10;

    {   // one-time V staging: thread -> V row k = tid>>1, d-half (tid&1)*32
        int k = tid >> 1;
        int tt = k >> 5, sk = k & 31;
        int d0 = (tid & 1) * 32;
        const unsigned short* src = Vg + (size_t)k * 2304 + d0;
#pragma unroll
        for (int c = 0; c < 4; ++c) {
            union { uint4 u; unsigned short s[8]; } vv;
            vv.u = *(const uint4*)(src + c * 8);
#pragma unroll
            for (int j = 0; j < 8; ++j) {
                int d = d0 + c * 8 + j;
                Vt[(tt * 64 + d) * 40 + (sk ^ (((d >> 3) & 3) << 3))] = vv.s[j];
            }
        }
    }

    bf16x8 qf[4];
#pragma unroll
    for (int c = 0; c < 4; ++c)
        qf[c] = *(const bf16x8*)(Qg + (size_t)(q0 + q) * 2304 + c * 16 + hh * 8);

    f32x16 o0 = (f32x16)0.f, o1 = (f32x16)0.f;
    float m = -3e38f, lsum = 0.f;
    const float SC = 0.125f * 1.44269504089f;

    bf16x8 kfA[4], kfB[4];
    auto loadK = [&](bf16x8 (&kf)[4], int tt) {
#pragma unroll
        for (int c = 0; c < 4; ++c)
            kf[c] = *(const bf16x8*)(Kg + (size_t)(tt * 32 + q) * 2304 + c * 16 + hh * 8);
    };
    loadK(kfA, 0);

    __syncthreads();   // Vt ready; no further block syncs

    auto process = [&](int t, bf16x8 (&kf)[4]) {
        f32x16 sacc = (f32x16)0.f;
#pragma unroll
        for (int c = 0; c < 4; ++c)
            sacc = __builtin_amdgcn_mfma_f32_32x32x16_bf16(kf[c], qf[c], sacc, 0, 0, 0);

        float p[16];
#pragma unroll
        for (int r = 0; r < 16; ++r) p[r] = sacc[r] * SC;
        float tm = fmaxf(
            fmaxf(fmaxf(fmaxf(p[0], p[1]), fmaxf(p[2], p[3])),
                  fmaxf(fmaxf(p[4], p[5]), fmaxf(p[6], p[7]))),
            fmaxf(fmaxf(fmaxf(p[8], p[9]), fmaxf(p[10], p[11])),
                  fmaxf(fmaxf(p[12], p[13]), fmaxf(p[14], p[15]))));
        tm = fmaxf(tm, __shfl_xor(tm, 32));
        if (!__all(tm <= m + 8.f)) {
            float mn = fmaxf(m, tm);
            float al = __builtin_amdgcn_exp2f(m - mn);
            lsum *= al;
#pragma unroll
            for (int r = 0; r < 16; ++r) { o0[r] *= al; o1[r] *= al; }
            m = mn;
        }
#pragma unroll
        for (int r = 0; r < 16; ++r) p[r] = __builtin_amdgcn_exp2f(p[r] - m);
        float rs =
            ((p[0] + p[1]) + (p[2] + p[3])) + ((p[4] + p[5]) + (p[6] + p[7])) +
            (((p[8] + p[9]) + (p[10] + p[11])) + ((p[12] + p[13]) + (p[14] + p[15])));
        lsum += rs;

        unsigned a0 = cvt_pk_bf16(p[0], p[1]);
        unsigned a1 = cvt_pk_bf16(p[2], p[3]);
        unsigned b0 = cvt_pk_bf16(p[4], p[5]);
        unsigned b1 = cvt_pk_bf16(p[6], p[7]);
        asm("v_permlane32_swap_b32 %0, %1" : "+v"(a0), "+v"(b0));
        asm("v_permlane32_swap_b32 %0, %1" : "+v"(a1), "+v"(b1));
        unsigned c0 = cvt_pk_bf16(p[8], p[9]);
        unsigned c1 = cvt_pk_bf16(p[10], p[11]);
        unsigned d0 = cvt_pk_bf16(p[12], p[13]);
        unsigned d1 = cvt_pk_bf16(p[14], p[15]);
        asm("v_permlane32_swap_b32 %0, %1" : "+v"(c0), "+v"(d0));
        asm("v_permlane32_swap_b32 %0, %1" : "+v"(c1), "+v"(d1));
        union { unsigned u[4]; bf16x8 v; } pf0, pf1;
        pf0.u[0] = a0; pf0.u[1] = a1; pf0.u[2] = b0; pf0.u[3] = b1;
        pf1.u[0] = c0; pf1.u[1] = c1; pf1.u[2] = d0; pf1.u[3] = d1;

        const unsigned short* vt = Vt + t * 2560;
        {
            int d = q;
            int sw = (d >> 3) & 3;
            bf16x8 va0 = *(const bf16x8*)&vt[d * 40 + ((0 + hh) ^ sw) * 8];
            bf16x8 va1 = *(const bf16x8*)&vt[d * 40 + ((2 + hh) ^ sw) * 8];
            o0 = __builtin_amdgcn_mfma_f32_32x32x16_bf16(va0, pf0.v, o0, 0, 0, 0);
            o0 = __builtin_amdgcn_mfma_f32_32x32x16_bf16(va1, pf1.v, o0, 0, 0, 0);
        }
        {
            int d = 32 + q;
            int sw = (d >> 3) & 3;
            bf16x8 va0 = *(const bf16x8*)&vt[d * 40 + ((0 + hh) ^ sw) * 8];
            bf16x8 va1 = *(const bf16x8*)&vt[d * 40 + ((2 + hh) ^ sw) * 8];
            o1 = __builtin_amdgcn_mfma_f32_32x32x16_bf16(va0, pf0.v, o1, 0, 0, 0);
            o1 = __builtin_amdgcn_mfma_f32_32x32x16_bf16(va1, pf1.v, o1, 0, 0, 0);
        }
    };

    for (int t = 0; t < ntile; t += 2) {
        loadK(kfB, t + 1);                       // overlaps tile t's softmax+PV
        process(t, kfA);
        loadK(kfA, (t + 2 < 10) ? (t + 2) : 8);  // overlaps tile t+1 (clamped, harmless)
        process(t + 1, kfB);
    }

    lsum += __shfl_xor(lsum, 32);
    float inv = 1.f / lsum;
    unsigned short* yp = y + (size_t)(bt * 320 + q0 + q) * 768 + h * 64;
#pragma unroll
    for (int r = 0; r < 16; r += 2) {
        int dr = (r & 3) + 8 * (r >> 2) + 4 * hh;
        *(unsigned*)(yp + dr) =
            (unsigned)f2bf(o0[r] * inv) | ((unsigned)f2bf(o0[r + 1] * inv) << 16);
        *(unsigned*)(yp + 32 + dr) =
            (unsigned)f2bf(o1[r] * inv) | ((unsigned)f2bf(o1[r + 1] * inv) << 16);
    }
}

// ---------------- launcher ----------------
extern "C" void kernel_launch(void* const* d_in, const int* in_sizes, int n_in,
                              void* d_out, int out_size, void* d_ws, size_t ws_size,
                              hipStream_t stream) {
    const float* x     = (const float*)d_in[0];
    const float* qkv_w = (const float*)d_in[1];
    const float* qkv_b = (const float*)d_in[2];
    const float* out_w = (const float*)d_in[3];
    const float* out_b = (const float*)d_in[4];

    const int M = 40960;  // B*T*S = 4*32*320
    unsigned short* xb  = (unsigned short*)d_ws;
    unsigned short* w1t = xb + (size_t)M * 768;           // [2304][768]
    unsigned short* w2t = w1t + (size_t)2304 * 768;       // [768][768]
    unsigned short* qkv = w2t + (size_t)768 * 768;        // [M][2304]
    unsigned short* yb  = qkv + (size_t)M * 2304;         // [M][768]

    k_convert<<<(M * 768 / 8 + 255) / 256, 256, 0, stream>>>(x, xb, M * 768 / 8);
    k_transpose<<<dim3(2304 / 32, 768 / 32), dim3(32, 8), 0, stream>>>(qkv_w, w1t, 768, 2304);
    k_transpose<<<dim3(768 / 32, 768 / 32), dim3(32, 8), 0, stream>>>(out_w, w2t, 768, 768);

    k_gemm256<true><<<(M / 256) * (2304 / 256), 512, 0, stream>>>(xb, w1t, qkv_b, (void*)qkv, M, 2304, 768);
    k_attn4<<<128 * 12, 640, 0, stream>>>(qkv, yb);
    k_gemm256<false><<<(M / 256) * (768 / 256), 512, 0, stream>>>(yb, w2t, out_b, d_out, M, 768, 768);
}

// Round 8
// 378.326 us; speedup vs baseline: 1.8431x; 1.0007x over previous
//
#include <hip/hip_runtime.h>

typedef __attribute__((ext_vector_type(8))) short bf16x8;
typedef __attribute__((ext_vector_type(4))) float f32x4;
typedef __attribute__((ext_vector_type(16))) float f32x16;
typedef __attribute__((address_space(1))) void gvoid_t;
typedef __attribute__((address_space(3))) void lvoid_t;

#define DEVI __device__ __forceinline__
#define SB __builtin_amdgcn_sched_barrier(0)

DEVI unsigned short f2bf(float f) {
    unsigned int u = __builtin_bit_cast(unsigned int, f);
    u += 0x7fffu + ((u >> 16) & 1u);   // RNE
    return (unsigned short)(u >> 16);
}

DEVI unsigned cvt_pk_bf16(float a, float b) {
    unsigned r;
    asm("v_cvt_pk_bf16_f32 %0, %1, %2" : "=v"(r) : "v"(a), "v"(b));
    return r;
}

DEVI f32x4 mfma16(bf16x8 a, bf16x8 b, f32x4 c) {
    return __builtin_amdgcn_mfma_f32_16x16x32_bf16(a, b, c, 0, 0, 0);
}

// ---------------- fp32 -> bf16 elementwise (8 elems/thread) ----------------
__global__ void k_convert(const float* __restrict__ in, unsigned short* __restrict__ out, int n8) {
    int i = blockIdx.x * 256 + threadIdx.x;
    if (i >= n8) return;
    const float4* p = (const float4*)in + (size_t)i * 2;
    float4 a = p[0], b = p[1];
    uint4 o;
    o.x = f2bf(a.x) | ((unsigned)f2bf(a.y) << 16);
    o.y = f2bf(a.z) | ((unsigned)f2bf(a.w) << 16);
    o.z = f2bf(b.x) | ((unsigned)f2bf(b.y) << 16);
    o.w = f2bf(b.z) | ((unsigned)f2bf(b.w) << 16);
    *((uint4*)out + i) = o;
}

// ---------------- transpose+convert: w[K][N] f32 -> wt[N][K] bf16 ----------------
__global__ void k_transpose(const float* __restrict__ w, unsigned short* __restrict__ wt, int K, int N) {
    __shared__ float tile[32][33];
    int n0 = blockIdx.x * 32, k0 = blockIdx.y * 32;
    int tx = threadIdx.x, ty = threadIdx.y;
#pragma unroll
    for (int r = 0; r < 32; r += 8)
        tile[ty + r][tx] = w[(size_t)(k0 + ty + r) * N + n0 + tx];
    __syncthreads();
#pragma unroll
    for (int r = 0; r < 32; r += 8)
        wt[(size_t)(n0 + ty + r) * K + k0 + tx] = f2bf(tile[tx][ty + r]);
}

// ---------------- K fragment-pack: kp[(bh*10+t)*4+c][lane][8] ----------------
// chunk (bh,t,c,lane l) = qkv[bt*320 + t*32 + (l&31)][768 + h*64 + c*16 + (l>>5)*8 ..+8]
__global__ __launch_bounds__(256) void k_kpack(const unsigned short* __restrict__ qkv,
                                               unsigned short* __restrict__ kp) {
    int bht = blockIdx.x;            // (bt*12+h)*10 + t
    int t = bht % 10, bh = bht / 10;
    int h = bh % 12, bt = bh / 12;
    int c = threadIdx.x >> 6, l = threadIdx.x & 63;
    const unsigned short* src = qkv + (size_t)(bt * 320 + t * 32 + (l & 31)) * 2304
                                + 768 + h * 64 + c * 16 + (l >> 5) * 8;
    uint4 v = *(const uint4*)src;
    *(uint4*)(kp + ((size_t)bht * 4 + c) * 512 + l * 8) = v;
}

// ---------------- 256x256 free-run bf16 GEMM: 1 barrier per K-tile ------------------
// 512 thr = 8 waves (2M x 4N); BK=64 double-buffered. Phases read bufR only, stage
// into bufW only -> intra-tile barriers removed; per-tile vmcnt(0)+barrier certifies.
// Stepped lgkmcnt waits pipeline ds_read drain under MFMA within each phase.
template <bool OUT_BF16>
__global__ __launch_bounds__(512, 2) void k_gemm256(const unsigned short* __restrict__ A,
                                                    const unsigned short* __restrict__ Bt,
                                                    const float* __restrict__ bias,
                                                    void* __restrict__ out,
                                                    int M, int N, int K) {
    __shared__ unsigned short smem[65536];   // A[2][256][64] @0, B[2][256][64] @32768

    const int tid = threadIdx.x;
    const int nwg = gridDim.x, bid = blockIdx.x;
    const int q8 = nwg >> 3, r8 = nwg & 7;
    const int xcd = bid & 7, lid = bid >> 3;
    const int swz = ((xcd < r8) ? xcd * (q8 + 1) : r8 * (q8 + 1) + (xcd - r8) * q8) + lid;
    const int ntn = N >> 8;
    const int bm = swz / ntn, bn = swz % ntn;

    const int lane = tid & 63, wid = tid >> 6;
    const int wr = wid >> 2, wc = wid & 3;
    const int lr = lane & 15, lg = lane >> 4;
    const int cswz = (lr & 7) << 3;
    const int col0 = (lg * 8) ^ cswz;

    const int NT = K >> 6;

    const int srowl = tid >> 3;
    const int scole = ((tid & 7) ^ (srowl & 7)) << 3;
    const unsigned short* aSrc = A  + (size_t)(bm * 256 + srowl) * K + scole;
    const unsigned short* bSrc = Bt + (size_t)(bn * 256 + srowl) * K + scole;

#define STG(matOff, srcBase, qq, koff, bufw)                                              \
    __builtin_amdgcn_global_load_lds((gvoid_t*)((srcBase) + (size_t)(qq) * 64 * K + (koff)), \
        (lvoid_t*)(smem + (matOff) + (bufw) * 16384 + (qq) * 4096 + tid * 8), 16, 0, 0)
#define LDA(mf, base, rowoff, kk) \
    *(const bf16x8*)((base) + ((rowoff) + (mf) * 16 + lr) * 64 + (col0 ^ ((kk) * 32)))

    f32x4 acc[8][4];
#pragma unroll
    for (int i = 0; i < 8; ++i)
#pragma unroll
        for (int j = 0; j < 4; ++j) acc[i][j] = (f32x4){0.f, 0.f, 0.f, 0.f};

    {   // prologue: tile0 fully + tile1 A0,A2
        const int k1 = (NT > 1) ? 64 : 0;
        STG(0, aSrc, 0, 0, 0); STG(0, aSrc, 1, 0, 0); STG(0, aSrc, 2, 0, 0); STG(0, aSrc, 3, 0, 0);
        STG(32768, bSrc, 0, 0, 0); STG(32768, bSrc, 1, 0, 0); STG(32768, bSrc, 2, 0, 0); STG(32768, bSrc, 3, 0, 0);
        STG(0, aSrc, 0, k1, 1); STG(0, aSrc, 2, k1, 1);
        asm volatile("s_waitcnt vmcnt(2)" ::: "memory");
        __builtin_amdgcn_s_barrier();
    }

#pragma unroll 1
    for (int t = 0; t < NT; ++t) {
        const int bufR = t & 1, bufW = bufR ^ 1;
        const int ko1 = (t + 1 < NT) ? (t + 1) * 64 : 0;
        const int ko2 = (t + 2 < NT) ? (t + 2) * 64 : 0;
        const unsigned short* abuf = smem + bufR * 16384;
        const unsigned short* bbuf = smem + 32768 + bufR * 16384;
        bf16x8 afv[4][2], b01[2][2], b23[2][2];

        // ===== P0: (mh=0) x (nh=0) =====
#pragma unroll
        for (int j = 0; j < 2; ++j)
#pragma unroll
            for (int kk = 0; kk < 2; ++kk)
                b01[j][kk] = LDA(j, bbuf, wc * 64, kk);
#pragma unroll
        for (int mf = 0; mf < 2; ++mf)
#pragma unroll
            for (int kk = 0; kk < 2; ++kk)
                afv[mf][kk] = LDA(mf, abuf, wr * 128, kk);
        SB;
#pragma unroll
        for (int mf = 2; mf < 4; ++mf)
#pragma unroll
            for (int kk = 0; kk < 2; ++kk)
                afv[mf][kk] = LDA(mf, abuf, wr * 128, kk);
        SB;
        STG(32768, bSrc, 0, ko1, bufW); STG(32768, bSrc, 1, ko1, bufW);
        asm volatile("s_waitcnt lgkmcnt(4)" ::: "memory"); SB;
        __builtin_amdgcn_s_setprio(1);
#pragma unroll
        for (int mf = 0; mf < 2; ++mf)
#pragma unroll
            for (int j = 0; j < 2; ++j)
#pragma unroll
                for (int kk = 0; kk < 2; ++kk)
                    acc[mf][j] = mfma16(afv[mf][kk], b01[j][kk], acc[mf][j]);
        __builtin_amdgcn_s_setprio(0);
        asm volatile("s_waitcnt lgkmcnt(0)" ::: "memory"); SB;
        __builtin_amdgcn_s_setprio(1);
#pragma unroll
        for (int mf = 2; mf < 4; ++mf)
#pragma unroll
            for (int j = 0; j < 2; ++j)
#pragma unroll
                for (int kk = 0; kk < 2; ++kk)
                    acc[mf][j] = mfma16(afv[mf][kk], b01[j][kk], acc[mf][j]);
        __builtin_amdgcn_s_setprio(0);

        // ===== P1: (mh=0) x (nh=1) =====
#pragma unroll
        for (int kk = 0; kk < 2; ++kk)
            b23[0][kk] = LDA(2, bbuf, wc * 64, kk);
        SB;
#pragma unroll
        for (int kk = 0; kk < 2; ++kk)
            b23[1][kk] = LDA(3, bbuf, wc * 64, kk);
        SB;
        STG(32768, bSrc, 2, ko1, bufW); STG(32768, bSrc, 3, ko1, bufW);
        asm volatile("s_waitcnt lgkmcnt(2)" ::: "memory"); SB;
        __builtin_amdgcn_s_setprio(1);
#pragma unroll
        for (int mf = 0; mf < 4; ++mf)
#pragma unroll
            for (int kk = 0; kk < 2; ++kk)
                acc[mf][2] = mfma16(afv[mf][kk], b23[0][kk], acc[mf][2]);
        __builtin_amdgcn_s_setprio(0);
        asm volatile("s_waitcnt lgkmcnt(0)" ::: "memory"); SB;
        __builtin_amdgcn_s_setprio(1);
#pragma unroll
        for (int mf = 0; mf < 4; ++mf)
#pragma unroll
            for (int kk = 0; kk < 2; ++kk)
                acc[mf][3] = mfma16(afv[mf][kk], b23[1][kk], acc[mf][3]);
        __builtin_amdgcn_s_setprio(0);

        // ===== P2: (mh=1) x (nh=1) =====
#pragma unroll
        for (int mf = 0; mf < 2; ++mf)
#pragma unroll
            for (int kk = 0; kk < 2; ++kk)
                afv[mf][kk] = LDA(mf, abuf, wr * 128 + 64, kk);
        SB;
#pragma unroll
        for (int mf = 2; mf < 4; ++mf)
#pragma unroll
            for (int kk = 0; kk < 2; ++kk)
                afv[mf][kk] = LDA(mf, abuf, wr * 128 + 64, kk);
        SB;
        STG(0, aSrc, 1, ko1, bufW); STG(0, aSrc, 3, ko1, bufW);
        asm volatile("s_waitcnt lgkmcnt(4)" ::: "memory"); SB;
        __builtin_amdgcn_s_setprio(1);
#pragma unroll
        for (int mf = 0; mf < 2; ++mf)
#pragma unroll
            for (int j = 0; j < 2; ++j)
#pragma unroll
                for (int kk = 0; kk < 2; ++kk)
                    acc[4 + mf][2 + j] = mfma16(afv[mf][kk], b23[j][kk], acc[4 + mf][2 + j]);
        __builtin_amdgcn_s_setprio(0);
        asm volatile("s_waitcnt lgkmcnt(0)" ::: "memory"); SB;
        __builtin_amdgcn_s_setprio(1);
#pragma unroll
        for (int mf = 2; mf < 4; ++mf)
#pragma unroll
            for (int j = 0; j < 2; ++j)
#pragma unroll
                for (int kk = 0; kk < 2; ++kk)
                    acc[4 + mf][2 + j] = mfma16(afv[mf][kk], b23[j][kk], acc[4 + mf][2 + j]);
        __builtin_amdgcn_s_setprio(0);

        // ===== P3: (mh=1) x (nh=0) — regs only =====
        __builtin_amdgcn_s_setprio(1);
#pragma unroll
        for (int mf = 0; mf < 4; ++mf)
#pragma unroll
            for (int j = 0; j < 2; ++j)
#pragma unroll
                for (int kk = 0; kk < 2; ++kk)
                    acc[4 + mf][j] = mfma16(afv[mf][kk], b01[j][kk], acc[4 + mf][j]);
        __builtin_amdgcn_s_setprio(0);
        // tile boundary: certify buf[t+1] for all waves, then stage t+2 A0/A2 into bufR
        asm volatile("s_waitcnt vmcnt(0)" ::: "memory");
        __builtin_amdgcn_s_barrier();
        STG(0, aSrc, 0, ko2, bufR); STG(0, aSrc, 2, ko2, bufR);
    }
#undef STG
#undef LDA

    // ---- epilogue: drain stray prefetches, block-sync, then LDS-staged stores ----
    asm volatile("s_waitcnt vmcnt(0)" ::: "memory");
    __syncthreads();
    float bv[4];
#pragma unroll
    for (int nf = 0; nf < 4; ++nf)
        bv[nf] = bias[bn * 256 + wc * 64 + nf * 16 + lr];

    if (OUT_BF16) {
        unsigned short* ebuf = smem + wid * 8192;      // 16KB apart (short units)
#pragma unroll
        for (int h = 0; h < 2; ++h) {
#pragma unroll
            for (int mf4 = 0; mf4 < 4; ++mf4) {
                int mf = h * 4 + mf4;
#pragma unroll
                for (int nf = 0; nf < 4; ++nf)
#pragma unroll
                    for (int i = 0; i < 4; ++i)
                        ebuf[(mf4 * 16 + lg * 4 + i) * 72 + nf * 16 + lr] = f2bf(acc[mf][nf][i] + bv[nf]);
            }
            asm volatile("s_waitcnt lgkmcnt(0)" ::: "memory"); SB;
#pragma unroll
            for (int ps = 0; ps < 8; ++ps) {
                int rl = ps * 8 + (lane >> 3), ck = lane & 7;
                uint4 vv = *(const uint4*)&ebuf[rl * 72 + ck * 8];
                int grow = bm * 256 + wr * 128 + h * 64 + rl;
                int gcol = bn * 256 + wc * 64 + ck * 8;
                *(uint4*)&((unsigned short*)out)[(size_t)grow * N + gcol] = vv;
            }
            asm volatile("s_waitcnt lgkmcnt(0)" ::: "memory"); SB;
        }
    } else {
        float* ebuf = (float*)smem + wid * 4096;
#pragma unroll
        for (int qq = 0; qq < 4; ++qq) {
#pragma unroll
            for (int m2 = 0; m2 < 2; ++m2) {
                int mf = qq * 2 + m2;
#pragma unroll
                for (int nf = 0; nf < 4; ++nf)
#pragma unroll
                    for (int i = 0; i < 4; ++i)
                        ebuf[(m2 * 16 + lg * 4 + i) * 68 + nf * 16 + lr] = acc[mf][nf][i] + bv[nf];
            }
            asm volatile("s_waitcnt lgkmcnt(0)" ::: "memory"); SB;
#pragma unroll
            for (int ps = 0; ps < 8; ++ps) {
                int rl = ps * 4 + (lane >> 4), ck = lane & 15;
                uint4 vv = *(const uint4*)&ebuf[rl * 68 + ck * 4];
                int grow = bm * 256 + wr * 128 + qq * 32 + rl;
                int gcol = bn * 256 + wc * 64 + ck * 4;
                *(uint4*)&((float*)out)[(size_t)grow * N + gcol] = vv;
            }
            asm volatile("s_waitcnt lgkmcnt(0)" ::: "memory"); SB;
        }
    }
}

// ---------------- fused flash attention v5: full-V LDS + packed-K coalesced loads ----
__global__ __launch_bounds__(640) void k_attn5(const unsigned short* __restrict__ qkv,
                                               const unsigned short* __restrict__ kp,
                                               unsigned short* __restrict__ y) {
    int bt = blockIdx.x / 12, h = blockIdx.x % 12;
    const unsigned short* Qg = qkv + (size_t)bt * 320 * 2304 + h * 64;
    const unsigned short* Vg = Qg + 1536;
    const unsigned short* Kpb = kp + (size_t)blockIdx.x * 20480;   // 10 tiles * 4c * 512

    __shared__ unsigned short Vt[10 * 64 * 40];   // [t][d][k'], swizzled per-tile

    int tid = threadIdx.x, w = tid >> 6, l = tid & 63;
    int q = l & 31, hh = l >> 5;
    int q0 = w * 32;
    int ntile = (w < 2) ? 2 : 10;

    {   // one-time V staging: thread -> V row k = tid>>1, d-half (tid&1)*32
        int k = tid >> 1;
        int tt = k >> 5, sk = k & 31;
        int d0 = (tid & 1) * 32;
        const unsigned short* src = Vg + (size_t)k * 2304 + d0;
#pragma unroll
        for (int c = 0; c < 4; ++c) {
            union { uint4 u; unsigned short s[8]; } vv;
            vv.u = *(const uint4*)(src + c * 8);
#pragma unroll
            for (int j = 0; j < 8; ++j) {
                int d = d0 + c * 8 + j;
                Vt[(tt * 64 + d) * 40 + (sk ^ (((d >> 3) & 3) << 3))] = vv.s[j];
            }
        }
    }

    bf16x8 qf[4];
#pragma unroll
    for (int c = 0; c < 4; ++c)
        qf[c] = *(const bf16x8*)(Qg + (size_t)(q0 + q) * 2304 + c * 16 + hh * 8);

    f32x16 o0 = (f32x16)0.f, o1 = (f32x16)0.f;
    float m = -3e38f, lsum = 0.f;
    const float SC = 0.125f * 1.44269504089f;

    bf16x8 kfA[4], kfB[4];
    auto loadK = [&](bf16x8 (&kf)[4], int tt) {
#pragma unroll
        for (int c = 0; c < 4; ++c)
            kf[c] = *(const bf16x8*)(Kpb + tt * 2048 + c * 512 + l * 8);
    };
    loadK(kfA, 0);

    __syncthreads();   // Vt ready; no further block syncs

    auto process = [&](int t, bf16x8 (&kf)[4]) {
        f32x16 sacc = (f32x16)0.f;
#pragma unroll
        for (int c = 0; c < 4; ++c)
            sacc = __builtin_amdgcn_mfma_f32_32x32x16_bf16(kf[c], qf[c], sacc, 0, 0, 0);

        float p[16];
#pragma unroll
        for (int r = 0; r < 16; ++r) p[r] = sacc[r] * SC;
        float tm = fmaxf(
            fmaxf(fmaxf(fmaxf(p[0], p[1]), fmaxf(p[2], p[3])),
                  fmaxf(fmaxf(p[4], p[5]), fmaxf(p[6], p[7]))),
            fmaxf(fmaxf(fmaxf(p[8], p[9]), fmaxf(p[10], p[11])),
                  fmaxf(fmaxf(p[12], p[13]), fmaxf(p[14], p[15]))));
        tm = fmaxf(tm, __shfl_xor(tm, 32));
        if (!__all(tm <= m + 8.f)) {
            float mn = fmaxf(m, tm);
            float al = __builtin_amdgcn_exp2f(m - mn);
            lsum *= al;
#pragma unroll
            for (int r = 0; r < 16; ++r) { o0[r] *= al; o1[r] *= al; }
            m = mn;
        }
#pragma unroll
        for (int r = 0; r < 16; ++r) p[r] = __builtin_amdgcn_exp2f(p[r] - m);
        float rs =
            ((p[0] + p[1]) + (p[2] + p[3])) + ((p[4] + p[5]) + (p[6] + p[7])) +
            (((p[8] + p[9]) + (p[10] + p[11])) + ((p[12] + p[13]) + (p[14] + p[15])));
        lsum += rs;

        unsigned a0 = cvt_pk_bf16(p[0], p[1]);
        unsigned a1 = cvt_pk_bf16(p[2], p[3]);
        unsigned b0 = cvt_pk_bf16(p[4], p[5]);
        unsigned b1 = cvt_pk_bf16(p[6], p[7]);
        asm("v_permlane32_swap_b32 %0, %1" : "+v"(a0), "+v"(b0));
        asm("v_permlane32_swap_b32 %0, %1" : "+v"(a1), "+v"(b1));
        unsigned c0 = cvt_pk_bf16(p[8], p[9]);
        unsigned c1 = cvt_pk_bf16(p[10], p[11]);
        unsigned d0 = cvt_pk_bf16(p[12], p[13]);
        unsigned d1 = cvt_pk_bf16(p[14], p[15]);
        asm("v_permlane32_swap_b32 %0, %1" : "+v"(c0), "+v"(d0));
        asm("v_permlane32_swap_b32 %0, %1" : "+v"(c1), "+v"(d1));
        union { unsigned u[4]; bf16x8 v; } pf0, pf1;
        pf0.u[0] = a0; pf0.u[1] = a1; pf0.u[2] = b0; pf0.u[3] = b1;
        pf1.u[0] = c0; pf1.u[1] = c1; pf1.u[2] = d0; pf1.u[3] = d1;

        const unsigned short* vt = Vt + t * 2560;
        {
            int d = q;
            int sw = (d >> 3) & 3;
            bf16x8 va0 = *(const bf16x8*)&vt[d * 40 + ((0 + hh) ^ sw) * 8];
            bf16x8 va1 = *(const bf16x8*)&vt[d * 40 + ((2 + hh) ^ sw) * 8];
            o0 = __builtin_amdgcn_mfma_f32_32x32x16_bf16(va0, pf0.v, o0, 0, 0, 0);
            o0 = __builtin_amdgcn_mfma_f32_32x32x16_bf16(va1, pf1.v, o0, 0, 0, 0);
        }
        {
            int d = 32 + q;
            int sw = (d >> 3) & 3;
            bf16x8 va0 = *(const bf16x8*)&vt[d * 40 + ((0 + hh) ^ sw) * 8];
            bf16x8 va1 = *(const bf16x8*)&vt[d * 40 + ((2 + hh) ^ sw) * 8];
            o1 = __builtin_amdgcn_mfma_f32_32x32x16_bf16(va0, pf0.v, o1, 0, 0, 0);
            o1 = __builtin_amdgcn_mfma_f32_32x32x16_bf16(va1, pf1.v, o1, 0, 0, 0);
        }
    };

    for (int t = 0; t < ntile; t += 2) {
        loadK(kfB, t + 1);
        process(t, kfA);
        loadK(kfA, (t + 2 < 10) ? (t + 2) : 8);
        process(t + 1, kfB);
    }

    lsum += __shfl_xor(lsum, 32);
    float inv = 1.f / lsum;
    unsigned short* yp = y + (size_t)(bt * 320 + q0 + q) * 768 + h * 64;
#pragma unroll
    for (int r = 0; r < 16; r += 2) {
        int dr = (r & 3) + 8 * (r >> 2) + 4 * hh;
        *(unsigned*)(yp + dr) =
            (unsigned)f2bf(o0[r] * inv) | ((unsigned)f2bf(o0[r + 1] * inv) << 16);
        *(unsigned*)(yp + 32 + dr) =
            (unsigned)f2bf(o1[r] * inv) | ((unsigned)f2bf(o1[r + 1] * inv) << 16);
    }
}

// ---------------- launcher ----------------
extern "C" void kernel_launch(void* const* d_in, const int* in_sizes, int n_in,
                              void* d_out, int out_size, void* d_ws, size_t ws_size,
                              hipStream_t stream) {
    const float* x     = (const float*)d_in[0];
    const float* qkv_w = (const float*)d_in[1];
    const float* qkv_b = (const float*)d_in[2];
    const float* out_w = (const float*)d_in[3];
    const float* out_b = (const float*)d_in[4];

    const int M = 40960;  // B*T*S = 4*32*320
    unsigned short* xb  = (unsigned short*)d_ws;
    unsigned short* w1t = xb + (size_t)M * 768;           // [2304][768]
    unsigned short* w2t = w1t + (size_t)2304 * 768;       // [768][768]
    unsigned short* qkv = w2t + (size_t)768 * 768;        // [M][2304]
    unsigned short* yb  = qkv + (size_t)M * 2304;         // [M][768]
    unsigned short* kp  = xb;                             // aliases xb (dead after gemm1): 15.7MB

    k_convert<<<(M * 768 / 8 + 255) / 256, 256, 0, stream>>>(x, xb, M * 768 / 8);
    k_transpose<<<dim3(2304 / 32, 768 / 32), dim3(32, 8), 0, stream>>>(qkv_w, w1t, 768, 2304);
    k_transpose<<<dim3(768 / 32, 768 / 32), dim3(32, 8), 0, stream>>>(out_w, w2t, 768, 768);

    k_gemm256<true><<<(M / 256) * (2304 / 256), 512, 0, stream>>>(xb, w1t, qkv_b, (void*)qkv, M, 2304, 768);
    k_kpack<<<1536 * 10, 256, 0, stream>>>(qkv, kp);
    k_attn5<<<128 * 12, 640, 0, stream>>>(qkv, kp, yb);
    k_gemm256<false><<<(M / 256) * (768 / 256), 512, 0, stream>>>(yb, w2t, out_b, d_out, M, 768, 768);
}